// Round 7
// baseline (3214.508 us; speedup 1.0000x reference)
//
#include <hip/hip_runtime.h>

typedef unsigned short u16;
typedef unsigned int u32;
typedef unsigned long long u64;

typedef short bf16x8 __attribute__((ext_vector_type(8)));
typedef float f32x4 __attribute__((ext_vector_type(4)));
typedef u32 u32x4 __attribute__((ext_vector_type(4)));

#define NB 64
#define NS 512
#define ND 768
#define NH 384
#define NT_OUT 22
#define S2 272           // materialized xg time extent (n[b] <= 256 < 272)
#define NG 1536          // 4*H
#define MGEMM (NB*S2)    // 17408
#define MAGIC 0x5A5AA5A5u
#define MAX_RETRY 1000000  // watchdog: visibility failure -> wrong answer, never a hang
#define NQC 6              // j-chunks per cluster (64 j each)

__device__ __forceinline__ u16 f2b(float f) {
    u32 u = __float_as_uint(f);
    u32 r = (u + 0x7fffu + ((u >> 16) & 1u)) >> 16;
    return (u16)r;
}
__device__ __forceinline__ float b2f(u16 s) { return __uint_as_float(((u32)s) << 16); }

__device__ __forceinline__ float sigm(float x) {
    return __builtin_amdgcn_rcpf(1.f + __expf(-x));
}
__device__ __forceinline__ float tanh_(float x) {
    return 1.f - 2.f * __builtin_amdgcn_rcpf(1.f + __expf(2.f * x));
}

__device__ __forceinline__ void gl_lds16(const void* g, void* l) {
    __builtin_amdgcn_global_load_lds(
        (const __attribute__((address_space(1))) unsigned int*)g,
        (__attribute__((address_space(3))) unsigned int*)l, 16, 0, 0);
}

// ---------------- exchange access helpers ----------------
// HW LESSON (R2 vs R4 A/B): plain global_load with sc0/sc1 can hit a STALE L1 line
// on gfx950 — a spinning poll never sees the remote write. `nt` (no L1 allocate) is
// what makes re-loads observe fresh L2 data. Fast path: sc0 nt loads / sc0 stores
// (meet at same-XCD L2). Slow path: compiler AGENT atomics (baseline-proven).
__device__ __forceinline__ u32 ld_sc0(const int* p) {
    u32 v;
    asm volatile("global_load_dword %0, %1, off sc0 nt\n\t"
                 "s_waitcnt vmcnt(0)"
                 : "=&v"(v) : "v"(p) : "memory");
    return v;
}
__device__ __forceinline__ void st_sc0(int* p, u32 v) {
    asm volatile("global_store_dword %0, %1, off sc0" :: "v"(p), "v"(v) : "memory");
}

// one chunk (64 j = 2 k-slices): 4x dwordx4 of tagged words, no wait
__device__ __forceinline__ void ld4_fast_nw(const u32* p,
        u32x4& A, u32x4& B, u32x4& C, u32x4& D) {
    asm volatile(
        "global_load_dwordx4 %0, %4, off sc0 nt\n\t"
        "global_load_dwordx4 %1, %4, off offset:16 sc0 nt\n\t"
        "global_load_dwordx4 %2, %4, off offset:128 sc0 nt\n\t"
        "global_load_dwordx4 %3, %4, off offset:144 sc0 nt"
        : "=&v"(A), "=&v"(B), "=&v"(C), "=&v"(D)
        : "v"(p) : "memory");
}
__device__ __forceinline__ void ld4_fast_wt(const u32* p,
        u32x4& A, u32x4& B, u32x4& C, u32x4& D) {
    asm volatile(
        "global_load_dwordx4 %0, %4, off sc0 nt\n\t"
        "global_load_dwordx4 %1, %4, off offset:16 sc0 nt\n\t"
        "global_load_dwordx4 %2, %4, off offset:128 sc0 nt\n\t"
        "global_load_dwordx4 %3, %4, off offset:144 sc0 nt\n\t"
        "s_waitcnt vmcnt(0)"
        : "=&v"(A), "=&v"(B), "=&v"(C), "=&v"(D)
        : "v"(p) : "memory");
}
__device__ __forceinline__ void ld4_slow(const u32* p,
        u32x4& A, u32x4& B, u32x4& C, u32x4& D) {
    #pragma unroll
    for (int e = 0; e < 4; e++) {
        A[e] = __hip_atomic_load(p + e,      __ATOMIC_RELAXED, __HIP_MEMORY_SCOPE_AGENT);
        B[e] = __hip_atomic_load(p + 4 + e,  __ATOMIC_RELAXED, __HIP_MEMORY_SCOPE_AGENT);
        C[e] = __hip_atomic_load(p + 32 + e, __ATOMIC_RELAXED, __HIP_MEMORY_SCOPE_AGENT);
        D[e] = __hip_atomic_load(p + 36 + e, __ATOMIC_RELAXED, __HIP_MEMORY_SCOPE_AGENT);
    }
}
__device__ __forceinline__ void ld4_nw(bool fast, const u32* p,
        u32x4& A, u32x4& B, u32x4& C, u32x4& D) {
    if (fast) ld4_fast_nw(p, A, B, C, D);
    else      ld4_slow(p, A, B, C, D);
}
__device__ __forceinline__ void ld4_wt(bool fast, const u32* p,
        u32x4& A, u32x4& B, u32x4& C, u32x4& D) {
    if (fast) ld4_fast_wt(p, A, B, C, D);
    else      ld4_slow(p, A, B, C, D);
}
#define WAIT_VM(N) do { __builtin_amdgcn_sched_barrier(0); \
    asm volatile("s_waitcnt vmcnt(" #N ")" ::: "memory"); \
    __builtin_amdgcn_sched_barrier(0); } while (0)

// sum of low-16 tags of 16 words; tags monotone (stale in {0, T-4}) so
// sum == 16*T  <=>  all 16 words carry tag T.
__device__ __forceinline__ u32 sum4(const u32x4& a, const u32x4& b,
                                    const u32x4& c, const u32x4& d) {
    u32 s = (a[0] & 0xffffu) + (a[1] & 0xffffu) + (a[2] & 0xffffu) + (a[3] & 0xffffu);
    s += (b[0] & 0xffffu) + (b[1] & 0xffffu) + (b[2] & 0xffffu) + (b[3] & 0xffffu);
    s += (c[0] & 0xffffu) + (c[1] & 0xffffu) + (c[2] & 0xffffu) + (c[3] & 0xffffu);
    s += (d[0] & 0xffffu) + (d[1] & 0xffffu) + (d[2] & 0xffffu) + (d[3] & 0xffffu);
    return s;
}
// pack 8 tagged words (h in high 16 bits) -> bf16x8 fragment
__device__ __forceinline__ bf16x8 packf(const u32x4& lo, const u32x4& hi) {
    union { u32 q[4]; bf16x8 v; } U;
    U.q[0] = __builtin_amdgcn_perm(lo[1], lo[0], 0x07060302u);
    U.q[1] = __builtin_amdgcn_perm(lo[3], lo[2], 0x07060302u);
    U.q[2] = __builtin_amdgcn_perm(hi[1], hi[0], 0x07060302u);
    U.q[3] = __builtin_amdgcn_perm(hi[3], hi[2], 0x07060302u);
    return U.v;
}

// ---------------- prep: align/gather -> embeds bf16 [64][272][768] ----------------
__global__ void k_prep(const float* __restrict__ hidden, const int* __restrict__ start_ids,
                       const int* __restrict__ masks, u16* __restrict__ embeds) {
    int b = blockIdx.x >> 2;
    int quarter = blockIdx.x & 3;
    int tid = threadIdx.x;
    __shared__ int red[256];
    int cn = 0, cm = 0;
    for (int s = tid; s < NS; s += 256) {
        cn += (start_ids[b * NS + s] >= 0) ? 1 : 0;
        cm += (masks[b * NS + s] != 0) ? 1 : 0;
    }
    red[tid] = cn + (cm << 16);
    __syncthreads();
    #pragma unroll
    for (int off = 128; off > 0; off >>= 1) {
        if (tid < off) red[tid] += red[tid + off];
        __syncthreads();
    }
    int n = red[0] & 0xffff;
    int slen = red[0] >> 16;
    n = min(max(n, 1), NS);
    int last = start_ids[b * NS + n - 1];
    for (int t = quarter * 68; t < quarter * 68 + 68; ++t) {
        int idx;
        if (t == 0) idx = 0;
        else if (t < n) idx = start_ids[b * NS + t] - 1;
        else if (t == n) idx = last;
        else idx = 0;
        idx = min(max(idx, 0), NS - 1);
        bool keep = t < slen;
        const float* src = hidden + ((size_t)b * NS + idx) * ND;
        u16* dst = embeds + ((size_t)b * S2 + t) * ND;
        if (tid < 192) {
            float4 v = keep ? *(const float4*)(src + tid * 4) : make_float4(0.f, 0.f, 0.f, 0.f);
            union { u16 u[4]; uint2 q; } pk;
            pk.u[0] = f2b(v.x); pk.u[1] = f2b(v.y); pk.u[2] = f2b(v.z); pk.u[3] = f2b(v.w);
            *(uint2*)(dst + tid * 4) = pk.q;
        }
    }
}

// ---------------- weights: cast W_ih (cat) to bf16, bias sums, h0 cast ----------------
__global__ void k_weights(const float* __restrict__ wf, const float* __restrict__ wb,
                          const float* __restrict__ bihf, const float* __restrict__ bhhf,
                          const float* __restrict__ bihb, const float* __restrict__ bhhb,
                          const float* __restrict__ h0,
                          u16* __restrict__ wihcat, float* __restrict__ biascat,
                          u16* __restrict__ h0buf) {
    int i0 = blockIdx.x * blockDim.x + threadIdx.x;
    int NTH = gridDim.x * blockDim.x;
    for (size_t i = i0; i < (size_t)2 * NG * ND; i += NTH) {
        size_t nrow = i / ND, k = i - nrow * ND;
        float v = (nrow < NG) ? wf[nrow * ND + k] : wb[(nrow - NG) * ND + k];
        wihcat[i] = f2b(v);
    }
    for (int i = i0; i < 2 * NG; i += NTH)
        biascat[i] = (i < NG) ? bihf[i] + bhhf[i] : bihb[i - NG] + bhhb[i - NG];
    for (int i = i0; i < 2 * NB * NH; i += NTH) h0buf[i] = f2b(h0[i]);
}

// ---------------- pack Whh into MFMA B-fragment order ----------------
// layout: [d][qc6][wj4][gate4][ks12][lane][8]
// (qc: 64-j chunk; wj: wave's 16-j slice; gate-local so the cell is register-local)
__global__ void k_packwhh(const float* __restrict__ whhf, const float* __restrict__ whhb,
                          u16* __restrict__ pack) {
    int ft = blockIdx.x * 256 + threadIdx.x;
    if (ft >= 2 * NQC * 4 * 4 * 12 * 64) return;
    int lane = ft & 63;
    int grp = ft >> 6;
    int ks = grp % 12; grp /= 12;
    int gate = grp & 3; grp >>= 2;
    int wj = grp & 3;  grp >>= 2;
    int qc = grp % NQC;
    int d  = grp / NQC;
    const float* W = d ? whhb : whhf;
    int col = gate * NH + qc * 64 + wj * 16 + (lane & 15);
    int k0 = ks * 32 + (lane >> 4) * 8;
    u16* dst = pack + (size_t)ft * 8;
    #pragma unroll
    for (int e = 0; e < 8; e++) dst[e] = f2b(W[(size_t)col * NH + k0 + e]);
}

// ---------------- GEMM: xg[d][b][t<272][1536] (bf16) = embeds @ WihcatT + bias ----------------
__launch_bounds__(256, 2)
__global__ void k_gemm(const u16* __restrict__ A, const u16* __restrict__ Bw,
                       const float* __restrict__ biascat, u16* __restrict__ xg) {
    __shared__ u16 As[128 * 32];
    __shared__ u16 Bs[128 * 32];
    int tid = threadIdx.x;
    int lane = tid & 63, wid = tid >> 6;
    int l15 = lane & 15, q4 = lane >> 4;
    int bn = blockIdx.x;   // 24 tiles of N=3072
    int bm = blockIdx.y;   // 136 tiles of M=17408
    int wm = (wid >> 1) * 64, wn = (wid & 1) * 64;
    f32x4 acc[4][4] = {};
    for (int k0 = 0; k0 < ND; k0 += 32) {
        #pragma unroll
        for (int j = 0; j < 2; j++) {
            int fl = tid + j * 256;
            int row = fl >> 2, cb = fl & 3;
            const u16* ga = A + (size_t)(bm * 128 + row) * ND + k0 + cb * 8;
            gl_lds16(ga, &As[(size_t)(wid * 64 + j * 256) * 8]);
            const u16* gb = Bw + (size_t)(bn * 128 + row) * ND + k0 + cb * 8;
            gl_lds16(gb, &Bs[(size_t)(wid * 64 + j * 256) * 8]);
        }
        __syncthreads();
        bf16x8 af[4], bf[4];
        #pragma unroll
        for (int mt = 0; mt < 4; mt++)
            af[mt] = *(const bf16x8*)&As[(wm + mt * 16 + l15) * 32 + q4 * 8];
        #pragma unroll
        for (int nt = 0; nt < 4; nt++)
            bf[nt] = *(const bf16x8*)&Bs[(wn + nt * 16 + l15) * 32 + q4 * 8];
        #pragma unroll
        for (int mt = 0; mt < 4; mt++)
            #pragma unroll
            for (int nt = 0; nt < 4; nt++)
                acc[mt][nt] = __builtin_amdgcn_mfma_f32_16x16x32_bf16(af[mt], bf[nt], acc[mt][nt], 0, 0, 0);
        __syncthreads();
    }
    #pragma unroll
    for (int nt = 0; nt < 4; nt++) {
        int gn = bn * 128 + wn + nt * 16 + l15;
        int d = gn >= NG ? 1 : 0;
        int col = gn - d * NG;
        float bias = biascat[gn];
        #pragma unroll
        for (int mt = 0; mt < 4; mt++) {
            #pragma unroll
            for (int r = 0; r < 4; r++) {
                int m = bm * 128 + wm + mt * 16 + q4 * 4 + r;
                int b = m / S2, t = m - b * S2;
                float v = acc[mt][nt][r] + bias;
                xg[((size_t)(d * NB + b) * S2 + t) * NG + col] = f2b(v);
            }
        }
    }
}

// ---------------- recurrence: BARRIER-FREE tag-synchronized ----------------
// 48 WGs; cluster = (dir, batch-group) of SIX 64-j WGs (blk%8 -> same-XCD heuristic).
// R7 structure (R6 analysis: step latency-bound at ~3260cy; repartition was a wash):
//  - GATE-LOCAL waves: each wave computes ALL 4 gates for a 16-j slice. acc[gate][r]
//    holds i,f,g,o for the same (batch,j) -> cell is pure register math.
//  - NO __syncthreads in the loop: own chunk also goes through the tagged exchange;
//    tags self-synchronize intra-WG (4 waves of one WG) AND inter-WG. 4-slot
//    rotation is safe: publishing tag T+4 implies all waves validated T+3.
//  - ci preloads are inline-asm with a strict vmcnt LEDGER (compiler scalar loads
//    caused vmcnt(0) full drains every step in R5/R6): per step, issue 24 chunk
//    loads -> WAIT(32) drains exactly the 16 ci -> acc init -> issue 16 next-ci ->
//    per-chunk counted waits 36/32/28/24/20/16.
// Protocol: tagged words (h<<16|tag), sc0-nt fast path, probe+consensus,
// agent-atomic fallback, retry watchdogs. MFMA K-order identical to R6 -> bit-same.
__launch_bounds__(256, 1)
__global__ void k_recur(const u16* __restrict__ whhpack, const u16* __restrict__ xg,
                        const float* __restrict__ biascat, const u16* __restrict__ h0buf,
                        const float* __restrict__ c0, u16* __restrict__ hout,
                        int* __restrict__ flags, u32* __restrict__ xch) {
    const int blk = blockIdx.x;      // 0..47
    const int qc = blk >> 3;         // j-chunk 0..5
    const int cl = blk & 7;          // cluster id
    const int d = cl >> 2;           // direction
    const int g = cl & 3;            // batch group (16 batches)
    const int tid = threadIdx.x, lane = tid & 63, w = tid >> 6;  // w = 16-j slice
    const int q4 = lane >> 4, l15 = lane & 15;

    __shared__ int s_fast;

    // stationary Whh B-fragments: bfr[gate][j], j=2i+(0|1) = (lo|hi) 32-k slice of
    // chunk (qc+i)%6. 48 frags = 192 VGPRs.
    bf16x8 bfr[4][12];
    #pragma unroll
    for (int gg = 0; gg < 4; gg++)
        #pragma unroll
        for (int j = 0; j < 12; j++) {
            int ksg = 2 * ((qc + (j >> 1)) % NQC) + (j & 1);
            bfr[gg][j] = *(const bf16x8*)(whhpack +
                ((size_t)((((d * NQC + qc) * 4 + w) * 4 + gg) * 12 + ksg) * 64 + lane) * 8);
        }

    // c-state: thread owns (batch=q4*4+r, j=w*16+l15), r=0..3
    float cre[4];
    #pragma unroll
    for (int r = 0; r < 4; r++)
        cre[r] = c0[(size_t)(d * NB + g * 16 + q4 * 4 + r) * NH + qc * 64 + w * 16 + l15];
    float biasreg[4];
    #pragma unroll
    for (int gg = 0; gg < 4; gg++)
        biasreg[gg] = biascat[d * NG + gg * NH + qc * 64 + w * 16 + l15];

    // ---- co-location probe + consensus (once per launch) ----
    if (tid == 0) {
        int* pzb = flags + cl * 128;          // probe words (6 used, 64B spread)
        int* pmb = flags + 2048 + cl * 128;   // consensus masks
        st_sc0(pzb + qc * 16, MAGIC);
        u32 seen = 1u << qc;
        for (int spin = 0; spin < 768 && seen != 0x3Fu; ++spin) {
            #pragma unroll
            for (int r = 0; r < NQC; ++r)
                if (!((seen >> r) & 1u) && ld_sc0(pzb + r * 16) == MAGIC) seen |= 1u << r;
            __builtin_amdgcn_s_sleep(2);
        }
        __hip_atomic_store(pmb + qc * 16, (int)(0x100u | seen),
                           __ATOMIC_RELAXED, __HIP_MEMORY_SCOPE_AGENT);
        u32 m = 0x3Fu;
        int spin2 = 0;
        #pragma unroll
        for (int r = 0; r < NQC; ++r) {
            u32 v;
            do {
                v = (u32)__hip_atomic_load(pmb + r * 16, __ATOMIC_RELAXED,
                                           __HIP_MEMORY_SCOPE_AGENT);
            } while (!(v & 0x100u) && ++spin2 < MAX_RETRY);
            m &= v;
        }
        s_fast = ((m & 0x3Fu) == 0x3Fu && spin2 < MAX_RETRY) ? 1 : 0;
    }
    __syncthreads();   // only barrier in the kernel
    const bool fast = (s_fast != 0);

    const u16* xgd = xg + (size_t)d * NB * S2 * NG;

    // ci preload: 16 asm ushort loads (gate-strided offsets 768B in a row), counted
    // in the vmcnt ledger. Always issues (clamped row) so the ledger is constant.
    u32 cr[4][4];
    auto issue_preload = [&](int it2) -> bool {
        int s2 = d ? (NS - 1 - it2) : it2;
        bool ok = (s2 >= 0) && (s2 < S2);
        int s2c = min(max(s2, 0), S2 - 1);
        const u16* rp = xgd + ((size_t)(g * 16 + q4 * 4) * S2 + s2c) * NG
                        + qc * 64 + w * 16 + l15;
        #pragma unroll
        for (int r = 0; r < 4; r++) {
            asm volatile(
                "global_load_ushort %0, %4, off\n\t"
                "global_load_ushort %1, %4, off offset:768\n\t"
                "global_load_ushort %2, %4, off offset:1536\n\t"
                "global_load_ushort %3, %4, off offset:2304"
                : "=&v"(cr[0][r]), "=&v"(cr[1][r]), "=&v"(cr[2][r]), "=&v"(cr[3][r])
                : "v"(rp) : "memory");
            rp += (size_t)S2 * NG;
        }
        return ok;
    };
    bool vld = issue_preload(0);

    #pragma unroll 1
    for (int it = 0; it < NS; ++it) {
        int s = d ? (NS - 1 - it) : it;
        f32x4 acc[4];

        if (it == 0) {
            WAIT_VM(0);   // ci(0) ready
            #pragma unroll
            for (int gg = 0; gg < 4; gg++)
                #pragma unroll
                for (int r = 0; r < 4; r++)
                    acc[gg][r] = vld ? __uint_as_float(cr[gg][r] << 16) : biasreg[gg];
            vld = issue_preload(1);
            const u16* hp = h0buf + (size_t)(d * NB + g * 16) * NH;
            #pragma unroll
            for (int j = 0; j < 12; j++) {
                int ksg = 2 * ((qc + (j >> 1)) % NQC) + (j & 1);
                bf16x8 af = *(const bf16x8*)(hp + (size_t)l15 * NH + ksg * 32 + q4 * 8);
                #pragma unroll
                for (int gg = 0; gg < 4; gg++)
                    acc[gg] = __builtin_amdgcn_mfma_f32_16x16x32_bf16(af, bfr[gg][j], acc[gg], 0, 0, 0);
            }
        } else {
            const u32 T = (u32)it;
            const u32 want = T * 16u;
            u32* xb = xch + (size_t)((T & 3u) * 8 + cl) * (NQC * 1024)
                          + (u32)(l15 * 64 + q4 * 8);
            u32* p0 = xb + qc * 1024;                    // own chunk, also via xch
            u32* p1 = xb + ((qc + 1) % NQC) * 1024;
            u32* p2 = xb + ((qc + 2) % NQC) * 1024;
            u32* p3 = xb + ((qc + 3) % NQC) * 1024;
            u32* p4 = xb + ((qc + 4) % NQC) * 1024;
            u32* p5 = xb + ((qc + 5) % NQC) * 1024;
            u32x4 r00, r01, r02, r03, r10, r11, r12, r13, r20, r21, r22, r23;
            u32x4 r30, r31, r32, r33, r40, r41, r42, r43, r50, r51, r52, r53;
            ld4_nw(fast, p0, r00, r01, r02, r03);
            ld4_nw(fast, p1, r10, r11, r12, r13);
            ld4_nw(fast, p2, r20, r21, r22, r23);
            ld4_nw(fast, p3, r30, r31, r32, r33);
            ld4_nw(fast, p4, r40, r41, r42, r43);
            ld4_nw(fast, p5, r50, r51, r52, r53);
            WAIT_VM(32);   // drains exactly the 16 ci(it) loads (oldest)
            #pragma unroll
            for (int gg = 0; gg < 4; gg++)
                #pragma unroll
                for (int r = 0; r < 4; r++)
                    acc[gg][r] = vld ? __uint_as_float(cr[gg][r] << 16) : biasreg[gg];
            vld = issue_preload(it + 1);
            int tries;
            // chunk 0 (own)
            WAIT_VM(36);
            tries = 0;
            while (!__all(sum4(r00, r01, r02, r03) == want) && ++tries < MAX_RETRY)
                ld4_wt(fast, p0, r00, r01, r02, r03);
            {
                bf16x8 lo = packf(r00, r01), hi = packf(r02, r03);
                #pragma unroll
                for (int gg = 0; gg < 4; gg++)
                    acc[gg] = __builtin_amdgcn_mfma_f32_16x16x32_bf16(lo, bfr[gg][0], acc[gg], 0, 0, 0);
                #pragma unroll
                for (int gg = 0; gg < 4; gg++)
                    acc[gg] = __builtin_amdgcn_mfma_f32_16x16x32_bf16(hi, bfr[gg][1], acc[gg], 0, 0, 0);
            }
            // chunk 1
            WAIT_VM(32);
            tries = 0;
            while (!__all(sum4(r10, r11, r12, r13) == want) && ++tries < MAX_RETRY)
                ld4_wt(fast, p1, r10, r11, r12, r13);
            {
                bf16x8 lo = packf(r10, r11), hi = packf(r12, r13);
                #pragma unroll
                for (int gg = 0; gg < 4; gg++)
                    acc[gg] = __builtin_amdgcn_mfma_f32_16x16x32_bf16(lo, bfr[gg][2], acc[gg], 0, 0, 0);
                #pragma unroll
                for (int gg = 0; gg < 4; gg++)
                    acc[gg] = __builtin_amdgcn_mfma_f32_16x16x32_bf16(hi, bfr[gg][3], acc[gg], 0, 0, 0);
            }
            // chunk 2
            WAIT_VM(28);
            tries = 0;
            while (!__all(sum4(r20, r21, r22, r23) == want) && ++tries < MAX_RETRY)
                ld4_wt(fast, p2, r20, r21, r22, r23);
            {
                bf16x8 lo = packf(r20, r21), hi = packf(r22, r23);
                #pragma unroll
                for (int gg = 0; gg < 4; gg++)
                    acc[gg] = __builtin_amdgcn_mfma_f32_16x16x32_bf16(lo, bfr[gg][4], acc[gg], 0, 0, 0);
                #pragma unroll
                for (int gg = 0; gg < 4; gg++)
                    acc[gg] = __builtin_amdgcn_mfma_f32_16x16x32_bf16(hi, bfr[gg][5], acc[gg], 0, 0, 0);
            }
            // chunk 3
            WAIT_VM(24);
            tries = 0;
            while (!__all(sum4(r30, r31, r32, r33) == want) && ++tries < MAX_RETRY)
                ld4_wt(fast, p3, r30, r31, r32, r33);
            {
                bf16x8 lo = packf(r30, r31), hi = packf(r32, r33);
                #pragma unroll
                for (int gg = 0; gg < 4; gg++)
                    acc[gg] = __builtin_amdgcn_mfma_f32_16x16x32_bf16(lo, bfr[gg][6], acc[gg], 0, 0, 0);
                #pragma unroll
                for (int gg = 0; gg < 4; gg++)
                    acc[gg] = __builtin_amdgcn_mfma_f32_16x16x32_bf16(hi, bfr[gg][7], acc[gg], 0, 0, 0);
            }
            // chunk 4
            WAIT_VM(20);
            tries = 0;
            while (!__all(sum4(r40, r41, r42, r43) == want) && ++tries < MAX_RETRY)
                ld4_wt(fast, p4, r40, r41, r42, r43);
            {
                bf16x8 lo = packf(r40, r41), hi = packf(r42, r43);
                #pragma unroll
                for (int gg = 0; gg < 4; gg++)
                    acc[gg] = __builtin_amdgcn_mfma_f32_16x16x32_bf16(lo, bfr[gg][8], acc[gg], 0, 0, 0);
                #pragma unroll
                for (int gg = 0; gg < 4; gg++)
                    acc[gg] = __builtin_amdgcn_mfma_f32_16x16x32_bf16(hi, bfr[gg][9], acc[gg], 0, 0, 0);
            }
            // chunk 5
            WAIT_VM(16);
            tries = 0;
            while (!__all(sum4(r50, r51, r52, r53) == want) && ++tries < MAX_RETRY)
                ld4_wt(fast, p5, r50, r51, r52, r53);
            {
                bf16x8 lo = packf(r50, r51), hi = packf(r52, r53);
                #pragma unroll
                for (int gg = 0; gg < 4; gg++)
                    acc[gg] = __builtin_amdgcn_mfma_f32_16x16x32_bf16(lo, bfr[gg][10], acc[gg], 0, 0, 0);
                #pragma unroll
                for (int gg = 0; gg < 4; gg++)
                    acc[gg] = __builtin_amdgcn_mfma_f32_16x16x32_bf16(hi, bfr[gg][11], acc[gg], 0, 0, 0);
            }
        }

        // cell update: fully register-local (acc[gate][r] = i,f,g,o of same (b,j))
        {
            u32 t2 = (u32)it + 1u;
            u32 tg0, tg1, tg2, tg3;
            u16 hv[4];
            #pragma unroll
            for (int r = 0; r < 4; r++) {
                float gi = acc[0][r], gf = acc[1][r];
                float gz = acc[2][r], go = acc[3][r];
                float c = cre[r];
                float cn = sigm(gf) * c + sigm(gi) * tanh_(gz);
                float hn = sigm(go) * tanh_(cn);
                cre[r] = cn;
                hv[r] = f2b(hn);
            }
            tg0 = ((u32)hv[0] << 16) | t2; tg1 = ((u32)hv[1] << 16) | t2;
            tg2 = ((u32)hv[2] << 16) | t2; tg3 = ((u32)hv[3] << 16) | t2;
            // output history (plain cached scalar stores, batch-strided)
            size_t hob = ((size_t)(d * NB + g * 16 + q4 * 4) * NS + s) * NH
                         + qc * 64 + w * 16 + l15;
            hout[hob] = hv[0];
            hout[hob + (size_t)NS * NH] = hv[1];
            hout[hob + (size_t)2 * NS * NH] = hv[2];
            hout[hob + (size_t)3 * NS * NH] = hv[3];
            // tagged publish: 4 dwords at batch stride 64 words (256 B)
            u32* xp = xch + (size_t)((t2 & 3u) * 8 + cl) * (NQC * 1024)
                          + (u32)(qc * 1024 + (q4 * 4) * 64 + w * 16 + l15);
            if (fast)
                asm volatile(
                    "global_store_dword %0, %1, off sc0\n\t"
                    "global_store_dword %0, %2, off offset:256 sc0\n\t"
                    "global_store_dword %0, %3, off offset:512 sc0\n\t"
                    "global_store_dword %0, %4, off offset:768 sc0"
                    :: "v"(xp), "v"(tg0), "v"(tg1), "v"(tg2), "v"(tg3) : "memory");
            else {
                __hip_atomic_store(xp,       tg0, __ATOMIC_RELAXED, __HIP_MEMORY_SCOPE_AGENT);
                __hip_atomic_store(xp + 64,  tg1, __ATOMIC_RELAXED, __HIP_MEMORY_SCOPE_AGENT);
                __hip_atomic_store(xp + 128, tg2, __ATOMIC_RELAXED, __HIP_MEMORY_SCOPE_AGENT);
                __hip_atomic_store(xp + 192, tg3, __ATOMIC_RELAXED, __HIP_MEMORY_SCOPE_AGENT);
            }
        }
        // no barrier: tags self-synchronize (intra-WG and inter-WG)
    }
}

// ---------------- final linear: out[b,t,22] = [hf|hb] @ WlinT + blin ----------------
__global__ void k_final(const u16* __restrict__ hout, const float* __restrict__ wlin,
                        const float* __restrict__ blin, float* __restrict__ out) {
    int r = blockIdx.x * 256 + threadIdx.x;   // 0..32767
    int b = r >> 9, t = r & 511;
    const u16* hf = hout + ((size_t)b * NS + t) * NH;
    const u16* hb = hout + ((size_t)(NB + b) * NS + t) * NH;
    float acc[NT_OUT];
    #pragma unroll
    for (int tt = 0; tt < NT_OUT; tt++) acc[tt] = blin[tt];
    #pragma unroll 1
    for (int half = 0; half < 2; half++) {
        const u16* hp = half ? hb : hf;
        #pragma unroll 1
        for (int k8 = 0; k8 < NH / 8; k8++) {
            uint4 pk = *(const uint4*)(hp + k8 * 8);
            float x[8];
            x[0] = __uint_as_float(pk.x << 16); x[1] = __uint_as_float(pk.x & 0xffff0000u);
            x[2] = __uint_as_float(pk.y << 16); x[3] = __uint_as_float(pk.y & 0xffff0000u);
            x[4] = __uint_as_float(pk.z << 16); x[5] = __uint_as_float(pk.z & 0xffff0000u);
            x[6] = __uint_as_float(pk.w << 16); x[7] = __uint_as_float(pk.w & 0xffff0000u);
            int kk = half * NH + k8 * 8;
            #pragma unroll
            for (int e = 0; e < 8; e++)
                #pragma unroll
                for (int tt = 0; tt < NT_OUT; tt++)
                    acc[tt] += x[e] * wlin[tt * (2 * NH) + kk + e];   // uniform -> s_load
        }
    }
    float* op = out + (size_t)r * NT_OUT;
    #pragma unroll
    for (int tt = 0; tt < NT_OUT; tt++) op[tt] = acc[tt];
}

extern "C" void kernel_launch(void* const* d_in, const int* in_sizes, int n_in,
                              void* d_out, int out_size, void* d_ws, size_t ws_size,
                              hipStream_t stream) {
    const float* hidden = (const float*)d_in[0];
    const float* h0     = (const float*)d_in[1];
    const float* c0     = (const float*)d_in[2];
    const float* Wihf   = (const float*)d_in[3];
    const float* Whhf   = (const float*)d_in[4];
    const float* bihf   = (const float*)d_in[5];
    const float* bhhf   = (const float*)d_in[6];
    const float* Wihb   = (const float*)d_in[7];
    const float* Whhb   = (const float*)d_in[8];
    const float* bihb   = (const float*)d_in[9];
    const float* bhhb   = (const float*)d_in[10];
    const float* Wlin   = (const float*)d_in[11];
    const float* blin   = (const float*)d_in[12];
    const int* start_ids = (const int*)d_in[13];
    const int* masks     = (const int*)d_in[14];
    float* out = (float*)d_out;

    char* ws = (char*)d_ws;
    size_t off = 0;
    auto alloc = [&](size_t bytes) { void* p = ws + off; off += (bytes + 255) & ~(size_t)255; return p; };
    u16* embeds   = (u16*)alloc((size_t)MGEMM * ND * 2);           // 26.7 MB
    u16* wihcat   = (u16*)alloc((size_t)2 * NG * ND * 2);          // 4.7 MB
    float* biascat = (float*)alloc((size_t)2 * NG * 4);            // 12 KB
    u16* whhpack  = (u16*)alloc((size_t)2 * NG * NH * 2);          // 2.36 MB
    u16* h0buf    = (u16*)alloc((size_t)2 * NB * NH * 2);          // 98 KB
    u16* xg       = (u16*)alloc((size_t)2 * NB * S2 * NG * 2);     // 107 MB
    u16* hout     = (u16*)alloc((size_t)2 * NB * NS * NH * 2);     // 50.3 MB
    int* flags    = (int*)alloc((size_t)8 * NS * 4);               // 16 KB (probe+consensus)
    u32* xch      = (u32*)alloc((size_t)4 * 8 * NQC * 1024 * 4);   // 768 KB tagged h exchange

    (void)hipMemsetAsync(flags, 0, (size_t)8 * NS * 4, stream);
    (void)hipMemsetAsync(xch, 0, (size_t)4 * 8 * NQC * 1024 * 4, stream);
    k_prep<<<256, 256, 0, stream>>>(hidden, start_ids, masks, embeds);
    k_weights<<<512, 256, 0, stream>>>(Wihf, Wihb, bihf, bhhf, bihb, bhhb, h0,
                                       wihcat, biascat, h0buf);
    k_packwhh<<<576, 256, 0, stream>>>(Whhf, Whhb, whhpack);
    dim3 ggrid(2 * NG / 128, MGEMM / 128);
    k_gemm<<<ggrid, 256, 0, stream>>>(embeds, wihcat, biascat, xg);
    k_recur<<<48, 256, 0, stream>>>(whhpack, xg, biascat, h0buf, c0, hout, flags, xch);
    k_final<<<128, 256, 0, stream>>>(hout, Wlin, blin, out);
}

// Round 8
// 2894.582 us; speedup vs baseline: 1.1105x; 1.1105x over previous
//
#include <hip/hip_runtime.h>

typedef unsigned short u16;
typedef unsigned int u32;
typedef unsigned long long u64;

typedef short bf16x8 __attribute__((ext_vector_type(8)));
typedef float f32x4 __attribute__((ext_vector_type(4)));
typedef u32 u32x4 __attribute__((ext_vector_type(4)));

#define NB 64
#define NS 512
#define ND 768
#define NH 384
#define NT_OUT 22
#define S2 272           // materialized xg time extent (n[b] <= 256 < 272)
#define NG 1536          // 4*H
#define MGEMM (NB*S2)    // 17408
#define MAGIC 0x5A5AA5A5u
#define MAX_RETRY 1000000  // watchdog: visibility failure -> wrong answer, never a hang

__device__ __forceinline__ u16 f2b(float f) {
    u32 u = __float_as_uint(f);
    u32 r = (u + 0x7fffu + ((u >> 16) & 1u)) >> 16;
    return (u16)r;
}
__device__ __forceinline__ float b2f(u16 s) { return __uint_as_float(((u32)s) << 16); }

__device__ __forceinline__ float sigm(float x) {
    return __builtin_amdgcn_rcpf(1.f + __expf(-x));
}
__device__ __forceinline__ float tanh_(float x) {
    return 1.f - 2.f * __builtin_amdgcn_rcpf(1.f + __expf(2.f * x));
}

__device__ __forceinline__ void gl_lds16(const void* g, void* l) {
    __builtin_amdgcn_global_load_lds(
        (const __attribute__((address_space(1))) unsigned int*)g,
        (__attribute__((address_space(3))) unsigned int*)l, 16, 0, 0);
}

// ---------------- exchange access helpers ----------------
// HW LESSON (R2 vs R4 A/B): plain global_load with sc0/sc1 can hit a STALE L1 line
// on gfx950 — a spinning poll never sees the remote write. `nt` (no L1 allocate) is
// what makes re-loads observe fresh L2 data. Fast path: sc0 nt loads / sc0 stores
// (meet at same-XCD L2). Slow path: compiler AGENT atomics (baseline-proven).
__device__ __forceinline__ u32 ld_sc0(const int* p) {
    u32 v;
    asm volatile("global_load_dword %0, %1, off sc0 nt\n\t"
                 "s_waitcnt vmcnt(0)"
                 : "=&v"(v) : "v"(p) : "memory");
    return v;
}
__device__ __forceinline__ void st_sc0(int* p, u32 v) {
    asm volatile("global_store_dword %0, %1, off sc0" :: "v"(p), "v"(v) : "memory");
}

// 6x dwordx4 of one sibling h-chunk (per lane: 3 k-slices x 8 tagged words), no wait
__device__ __forceinline__ void ld6_fast_nw(const u32* p,
        u32x4& A, u32x4& B, u32x4& C, u32x4& D, u32x4& E, u32x4& F) {
    asm volatile(
        "global_load_dwordx4 %0, %6, off sc0 nt\n\t"
        "global_load_dwordx4 %1, %6, off offset:16 sc0 nt\n\t"
        "global_load_dwordx4 %2, %6, off offset:128 sc0 nt\n\t"
        "global_load_dwordx4 %3, %6, off offset:144 sc0 nt\n\t"
        "global_load_dwordx4 %4, %6, off offset:256 sc0 nt\n\t"
        "global_load_dwordx4 %5, %6, off offset:272 sc0 nt"
        : "=&v"(A), "=&v"(B), "=&v"(C), "=&v"(D), "=&v"(E), "=&v"(F)
        : "v"(p) : "memory");
}
__device__ __forceinline__ void ld6_fast_wt(const u32* p,
        u32x4& A, u32x4& B, u32x4& C, u32x4& D, u32x4& E, u32x4& F) {
    asm volatile(
        "global_load_dwordx4 %0, %6, off sc0 nt\n\t"
        "global_load_dwordx4 %1, %6, off offset:16 sc0 nt\n\t"
        "global_load_dwordx4 %2, %6, off offset:128 sc0 nt\n\t"
        "global_load_dwordx4 %3, %6, off offset:144 sc0 nt\n\t"
        "global_load_dwordx4 %4, %6, off offset:256 sc0 nt\n\t"
        "global_load_dwordx4 %5, %6, off offset:272 sc0 nt\n\t"
        "s_waitcnt vmcnt(0)"
        : "=&v"(A), "=&v"(B), "=&v"(C), "=&v"(D), "=&v"(E), "=&v"(F)
        : "v"(p) : "memory");
}
// slow path: correctness-guaranteed AGENT atomics (blocking; fallback only)
__device__ __forceinline__ void ld6_slow(const u32* p,
        u32x4& A, u32x4& B, u32x4& C, u32x4& D, u32x4& E, u32x4& F) {
    #pragma unroll
    for (int e = 0; e < 4; e++) {
        A[e] = __hip_atomic_load(p + e,      __ATOMIC_RELAXED, __HIP_MEMORY_SCOPE_AGENT);
        B[e] = __hip_atomic_load(p + 4 + e,  __ATOMIC_RELAXED, __HIP_MEMORY_SCOPE_AGENT);
        C[e] = __hip_atomic_load(p + 32 + e, __ATOMIC_RELAXED, __HIP_MEMORY_SCOPE_AGENT);
        D[e] = __hip_atomic_load(p + 36 + e, __ATOMIC_RELAXED, __HIP_MEMORY_SCOPE_AGENT);
        E[e] = __hip_atomic_load(p + 64 + e, __ATOMIC_RELAXED, __HIP_MEMORY_SCOPE_AGENT);
        F[e] = __hip_atomic_load(p + 68 + e, __ATOMIC_RELAXED, __HIP_MEMORY_SCOPE_AGENT);
    }
}
__device__ __forceinline__ void ld6_nw(bool fast, const u32* p,
        u32x4& A, u32x4& B, u32x4& C, u32x4& D, u32x4& E, u32x4& F) {
    if (fast) ld6_fast_nw(p, A, B, C, D, E, F);
    else      ld6_slow(p, A, B, C, D, E, F);
}
__device__ __forceinline__ void ld6_wt(bool fast, const u32* p,
        u32x4& A, u32x4& B, u32x4& C, u32x4& D, u32x4& E, u32x4& F) {
    if (fast) ld6_fast_wt(p, A, B, C, D, E, F);
    else      ld6_slow(p, A, B, C, D, E, F);
}
__device__ __forceinline__ void st8(bool fast, u32* p, u32x4 lo, u32x4 hi) {
    if (fast)
        asm volatile("global_store_dwordx4 %0, %1, off sc0\n\t"
                     "global_store_dwordx4 %0, %2, off offset:16 sc0"
                     :: "v"(p), "v"(lo), "v"(hi) : "memory");
    else {
        #pragma unroll
        for (int e = 0; e < 4; e++) {
            __hip_atomic_store(p + e,     lo[e], __ATOMIC_RELAXED, __HIP_MEMORY_SCOPE_AGENT);
            __hip_atomic_store(p + 4 + e, hi[e], __ATOMIC_RELAXED, __HIP_MEMORY_SCOPE_AGENT);
        }
    }
}
#define WAIT_VM(N) do { __builtin_amdgcn_sched_barrier(0); \
    asm volatile("s_waitcnt vmcnt(" #N ")" ::: "memory"); \
    __builtin_amdgcn_sched_barrier(0); } while (0)
// LDS-only barrier (global exchange is self-validating; no vm drain)
__device__ __forceinline__ void ldsbar() {
    asm volatile("s_waitcnt lgkmcnt(0)" ::: "memory");
    __builtin_amdgcn_s_barrier();
    __builtin_amdgcn_sched_barrier(0);
}

// sum of low-16 tags of 24 words; tags monotone (stale in {0, T-4}) so
// sum == 24*T  <=>  all 24 words carry tag T.
__device__ __forceinline__ u32 sum6(const u32x4& a, const u32x4& b, const u32x4& c,
                                    const u32x4& d, const u32x4& e, const u32x4& f) {
    u32 s = (a[0] & 0xffffu) + (a[1] & 0xffffu) + (a[2] & 0xffffu) + (a[3] & 0xffffu);
    s += (b[0] & 0xffffu) + (b[1] & 0xffffu) + (b[2] & 0xffffu) + (b[3] & 0xffffu);
    s += (c[0] & 0xffffu) + (c[1] & 0xffffu) + (c[2] & 0xffffu) + (c[3] & 0xffffu);
    s += (d[0] & 0xffffu) + (d[1] & 0xffffu) + (d[2] & 0xffffu) + (d[3] & 0xffffu);
    s += (e[0] & 0xffffu) + (e[1] & 0xffffu) + (e[2] & 0xffffu) + (e[3] & 0xffffu);
    s += (f[0] & 0xffffu) + (f[1] & 0xffffu) + (f[2] & 0xffffu) + (f[3] & 0xffffu);
    return s;
}
// pack 8 tagged words (h in high 16 bits) -> bf16x8 fragment
__device__ __forceinline__ bf16x8 packf(const u32x4& lo, const u32x4& hi) {
    union { u32 q[4]; bf16x8 v; } U;
    U.q[0] = __builtin_amdgcn_perm(lo[1], lo[0], 0x07060302u);
    U.q[1] = __builtin_amdgcn_perm(lo[3], lo[2], 0x07060302u);
    U.q[2] = __builtin_amdgcn_perm(hi[1], hi[0], 0x07060302u);
    U.q[3] = __builtin_amdgcn_perm(hi[3], hi[2], 0x07060302u);
    return U.v;
}

// ---------------- prep: align/gather -> embeds bf16 [64][272][768] ----------------
__global__ void k_prep(const float* __restrict__ hidden, const int* __restrict__ start_ids,
                       const int* __restrict__ masks, u16* __restrict__ embeds) {
    int b = blockIdx.x >> 2;
    int quarter = blockIdx.x & 3;
    int tid = threadIdx.x;
    __shared__ int red[256];
    int cn = 0, cm = 0;
    for (int s = tid; s < NS; s += 256) {
        cn += (start_ids[b * NS + s] >= 0) ? 1 : 0;
        cm += (masks[b * NS + s] != 0) ? 1 : 0;
    }
    red[tid] = cn + (cm << 16);
    __syncthreads();
    #pragma unroll
    for (int off = 128; off > 0; off >>= 1) {
        if (tid < off) red[tid] += red[tid + off];
        __syncthreads();
    }
    int n = red[0] & 0xffff;
    int slen = red[0] >> 16;
    n = min(max(n, 1), NS);
    int last = start_ids[b * NS + n - 1];
    for (int t = quarter * 68; t < quarter * 68 + 68; ++t) {
        int idx;
        if (t == 0) idx = 0;
        else if (t < n) idx = start_ids[b * NS + t] - 1;
        else if (t == n) idx = last;
        else idx = 0;
        idx = min(max(idx, 0), NS - 1);
        bool keep = t < slen;
        const float* src = hidden + ((size_t)b * NS + idx) * ND;
        u16* dst = embeds + ((size_t)b * S2 + t) * ND;
        if (tid < 192) {
            float4 v = keep ? *(const float4*)(src + tid * 4) : make_float4(0.f, 0.f, 0.f, 0.f);
            union { u16 u[4]; uint2 q; } pk;
            pk.u[0] = f2b(v.x); pk.u[1] = f2b(v.y); pk.u[2] = f2b(v.z); pk.u[3] = f2b(v.w);
            *(uint2*)(dst + tid * 4) = pk.q;
        }
    }
}

// ---------------- weights: cast W_ih (cat) to bf16, bias sums, h0 cast ----------------
__global__ void k_weights(const float* __restrict__ wf, const float* __restrict__ wb,
                          const float* __restrict__ bihf, const float* __restrict__ bhhf,
                          const float* __restrict__ bihb, const float* __restrict__ bhhb,
                          const float* __restrict__ h0,
                          u16* __restrict__ wihcat, float* __restrict__ biascat,
                          u16* __restrict__ h0buf) {
    int i0 = blockIdx.x * blockDim.x + threadIdx.x;
    int NTH = gridDim.x * blockDim.x;
    for (size_t i = i0; i < (size_t)2 * NG * ND; i += NTH) {
        size_t nrow = i / ND, k = i - nrow * ND;
        float v = (nrow < NG) ? wf[nrow * ND + k] : wb[(nrow - NG) * ND + k];
        wihcat[i] = f2b(v);
    }
    for (int i = i0; i < 2 * NG; i += NTH)
        biascat[i] = (i < NG) ? bihf[i] + bhhf[i] : bihb[i - NG] + bhhb[i - NG];
    for (int i = i0; i < 2 * NB * NH; i += NTH) h0buf[i] = f2b(h0[i]);
}

// ---------------- pack Whh into MFMA B-fragment order ----------------
// layout: [d][qc][w][nt][ks][lane][8]  (d:2, qc:4 j-chunk, w:4 gate, nt:6, ks:12)
__global__ void k_packwhh(const float* __restrict__ whhf, const float* __restrict__ whhb,
                          u16* __restrict__ pack) {
    int ft = blockIdx.x * 256 + threadIdx.x;
    if (ft >= 2 * 4 * 4 * 6 * 12 * 64) return;
    int lane = ft & 63;
    int grp = ft >> 6;
    int ks = grp % 12; grp /= 12;
    int nt = grp % 6;  grp /= 6;
    int w  = grp & 3;  grp >>= 2;
    int qc = grp & 3;
    int d  = grp >> 2;
    const float* W = d ? whhb : whhf;
    int col = w * NH + qc * 96 + nt * 16 + (lane & 15);
    int k0 = ks * 32 + (lane >> 4) * 8;
    u16* dst = pack + (size_t)ft * 8;
    #pragma unroll
    for (int e = 0; e < 8; e++) dst[e] = f2b(W[(size_t)col * NH + k0 + e]);
}

// ---------------- GEMM: xg[d][b][t<272][1536] (bf16) = embeds @ WihcatT + bias ----------------
__launch_bounds__(256, 2)
__global__ void k_gemm(const u16* __restrict__ A, const u16* __restrict__ Bw,
                       const float* __restrict__ biascat, u16* __restrict__ xg) {
    __shared__ u16 As[128 * 32];
    __shared__ u16 Bs[128 * 32];
    int tid = threadIdx.x;
    int lane = tid & 63, wid = tid >> 6;
    int l15 = lane & 15, q4 = lane >> 4;
    int bn = blockIdx.x;   // 24 tiles of N=3072
    int bm = blockIdx.y;   // 136 tiles of M=17408
    int wm = (wid >> 1) * 64, wn = (wid & 1) * 64;
    f32x4 acc[4][4] = {};
    for (int k0 = 0; k0 < ND; k0 += 32) {
        #pragma unroll
        for (int j = 0; j < 2; j++) {
            int fl = tid + j * 256;
            int row = fl >> 2, cb = fl & 3;
            const u16* ga = A + (size_t)(bm * 128 + row) * ND + k0 + cb * 8;
            gl_lds16(ga, &As[(size_t)(wid * 64 + j * 256) * 8]);
            const u16* gb = Bw + (size_t)(bn * 128 + row) * ND + k0 + cb * 8;
            gl_lds16(gb, &Bs[(size_t)(wid * 64 + j * 256) * 8]);
        }
        __syncthreads();
        bf16x8 af[4], bf[4];
        #pragma unroll
        for (int mt = 0; mt < 4; mt++)
            af[mt] = *(const bf16x8*)&As[(wm + mt * 16 + l15) * 32 + q4 * 8];
        #pragma unroll
        for (int nt = 0; nt < 4; nt++)
            bf[nt] = *(const bf16x8*)&Bs[(wn + nt * 16 + l15) * 32 + q4 * 8];
        #pragma unroll
        for (int mt = 0; mt < 4; mt++)
            #pragma unroll
            for (int nt = 0; nt < 4; nt++)
                acc[mt][nt] = __builtin_amdgcn_mfma_f32_16x16x32_bf16(af[mt], bf[nt], acc[mt][nt], 0, 0, 0);
        __syncthreads();
    }
    #pragma unroll
    for (int nt = 0; nt < 4; nt++) {
        int gn = bn * 128 + wn + nt * 16 + l15;
        int d = gn >= NG ? 1 : 0;
        int col = gn - d * NG;
        float bias = biascat[gn];
        #pragma unroll
        for (int mt = 0; mt < 4; mt++) {
            #pragma unroll
            for (int r = 0; r < 4; r++) {
                int m = bm * 128 + wm + mt * 16 + q4 * 4 + r;
                int b = m / S2, t = m - b * S2;
                float v = acc[mt][nt][r] + bias;
                xg[((size_t)(d * NB + b) * S2 + t) * NG + col] = f2b(v);
            }
        }
    }
}

// ---------------- recurrence: R2 structure + asm-ci vmcnt LEDGER ----------------
// 32 WGs; cluster = (dir, batch-group) of 4 j-chunk WGs (blk%8 -> same-XCD heuristic).
// R8 = best-known structure (R2: 4-WG, own chunk in LDS, LDS preact, lgkm-only
// barriers, tagged sc0-nt exchange, no end drain) + ONE fix: ci preloads are raw
// asm ushort loads in a strict vmcnt ledger. In R2/R5/R6 the compiler placed its
// vmcnt(0) for the (L3-resident, ~600cy) xg loads right before the cell/publish
// phase -> every step's publish was delayed by an L3 latency -> sibling polls
// missed -> retry cascade. Ledger per step: issue 18 exch -> WAIT(18) drains the
// 24 old ci (+3 old stores, in-order vmcnt) -> acc init -> issue next ci ->
// counted waits 36/30/24 for chunks A/B/C.
__launch_bounds__(256, 1)
__global__ void k_recur(const u16* __restrict__ whhpack, const u16* __restrict__ xg,
                        const float* __restrict__ biascat, const u16* __restrict__ h0buf,
                        const float* __restrict__ c0, u16* __restrict__ hout,
                        int* __restrict__ flags, u32* __restrict__ xch) {
    const int blk = blockIdx.x;      // 0..31
    const int qc = blk >> 3;         // j-chunk 0..3
    const int cl = blk & 7;          // cluster id
    const int d = cl >> 2;           // direction
    const int g = cl & 3;            // batch group (16 batches)
    const int tid = threadIdx.x, lane = tid & 63, w = tid >> 6;  // wave = gate i,f,g,o
    const int q4 = lane >> 4, l15 = lane & 15;

    __shared__ float preact[4][16 * 100];  // pad 96->100: kill 4-way bank aliasing
    __shared__ u16 hlds[16 * 104];         // own h chunk, padded stride 104
    __shared__ int s_fast;

    // stationary Whh B-fragments, SIBLING-PERMUTED ks order: j=0..2 own chunk,
    // 3..5 sib(qc+1), 6..8 sib(qc+2), 9..11 sib(qc+3).
    bf16x8 bfr[6][12];
    #pragma unroll
    for (int nt = 0; nt < 6; nt++)
        #pragma unroll
        for (int j = 0; j < 12; j++) {
            int ksg = ((qc + (j / 3)) & 3) * 3 + (j % 3);
            bfr[nt][j] = *(const bf16x8*)(whhpack +
                ((size_t)((((d * 4 + qc) * 4 + w) * 6 + nt) * 12 + ksg) * 64 + lane) * 8);
        }

    // c-state in registers: 192 threads x 8 contiguous j-elements
    const int bb = tid / 12;              // batch within group (tid<192)
    const int j0 = (tid % 12) * 8;        // j offset within 96-chunk
    float cre[8];
    if (tid < 192) {
        const float* cp = c0 + (size_t)(d * NB + g * 16 + bb) * NH + qc * 96 + j0;
        #pragma unroll
        for (int e = 0; e < 8; e++) cre[e] = cp[e];
    }
    float biasreg[6];
    #pragma unroll
    for (int nt = 0; nt < 6; nt++)
        biasreg[nt] = biascat[d * NG + w * NH + qc * 96 + nt * 16 + l15];

    // ---- co-location probe + consensus (once per launch) ----
    if (tid == 0) {
        int* pzb = flags + cl * 64;          // probe words, 64B-line spread
        int* pmb = flags + 2048 + cl * 64;   // consensus masks
        st_sc0(pzb + qc * 16, MAGIC);
        u32 seen = 1u << qc;
        for (int spin = 0; spin < 512 && seen != 0xFu; ++spin) {
            #pragma unroll
            for (int r = 0; r < 4; ++r)
                if (!((seen >> r) & 1u) && ld_sc0(pzb + r * 16) == MAGIC) seen |= 1u << r;
            __builtin_amdgcn_s_sleep(2);
        }
        __hip_atomic_store(pmb + qc * 16, (int)(0x100u | seen),
                           __ATOMIC_RELAXED, __HIP_MEMORY_SCOPE_AGENT);
        u32 m = 0xFu;
        int spin2 = 0;
        #pragma unroll
        for (int r = 0; r < 4; ++r) {
            u32 v;
            do {
                v = (u32)__hip_atomic_load(pmb + r * 16, __ATOMIC_RELAXED,
                                           __HIP_MEMORY_SCOPE_AGENT);
            } while (!(v & 0x100u) && ++spin2 < MAX_RETRY);
            m &= v;
        }
        s_fast = ((m & 0xFu) == 0xFu && spin2 < MAX_RETRY) ? 1 : 0;
    }
    __syncthreads();
    const bool fast = (s_fast != 0);

    const u16* xgd = xg + (size_t)d * NB * S2 * NG;

    // ci preload: 24 asm ushort loads (6 nt-cols x 4 batch-rows), counted in the
    // vmcnt ledger. Always issues (clamped row) so the ledger is constant.
    u32 cr[6][4];
    auto issue_preload = [&](int it2) -> bool {
        int s2 = d ? (NS - 1 - it2) : it2;
        bool ok = (s2 >= 0) && (s2 < S2);
        int s2c = min(max(s2, 0), S2 - 1);
        const u16* rp = xgd + ((size_t)(g * 16) * S2 + s2c) * NG + w * NH + qc * 96 + l15;
        #pragma unroll
        for (int r = 0; r < 4; r++) {
            const u16* base = rp + (size_t)(q4 * 4 + r) * S2 * NG;
            asm volatile(
                "global_load_ushort %0, %6, off\n\t"
                "global_load_ushort %1, %6, off offset:32\n\t"
                "global_load_ushort %2, %6, off offset:64\n\t"
                "global_load_ushort %3, %6, off offset:96\n\t"
                "global_load_ushort %4, %6, off offset:128\n\t"
                "global_load_ushort %5, %6, off offset:160"
                : "=&v"(cr[0][r]), "=&v"(cr[1][r]), "=&v"(cr[2][r]),
                  "=&v"(cr[3][r]), "=&v"(cr[4][r]), "=&v"(cr[5][r])
                : "v"(base) : "memory");
        }
        return ok;
    };
    bool vld = issue_preload(0);

    #pragma unroll 1
    for (int it = 0; it < NS; ++it) {
        int s = d ? (NS - 1 - it) : it;
        f32x4 acc[6];

        if (it == 0) {
            WAIT_VM(0);   // ci(0) ready
            #pragma unroll
            for (int nt = 0; nt < 6; nt++)
                #pragma unroll
                for (int r = 0; r < 4; r++)
                    acc[nt][r] = vld ? __uint_as_float(cr[nt][r] << 16) : biasreg[nt];
            vld = issue_preload(1);
            const u16* hp = h0buf + (size_t)(d * NB + g * 16) * NH;
            #pragma unroll
            for (int j = 0; j < 12; j++) {
                int ksg = ((qc + (j / 3)) & 3) * 3 + (j % 3);
                bf16x8 af = *(const bf16x8*)(hp + (size_t)l15 * NH + ksg * 32 + q4 * 8);
                #pragma unroll
                for (int nt = 0; nt < 6; nt++)
                    acc[nt] = __builtin_amdgcn_mfma_f32_16x16x32_bf16(af, bfr[nt][j], acc[nt], 0, 0, 0);
            }
        } else {
            const u32 T = (u32)it;
            const u32 want = T * 24u;
            u32* xrow = xch + (((size_t)(T & 3u) * 8 + cl) * 16 + l15) * 384 + q4 * 8;
            u32* pA = xrow + ((qc + 1) & 3) * 96;
            u32* pB = xrow + ((qc + 2) & 3) * 96;
            u32* pC = xrow + ((qc + 3) & 3) * 96;
            u32x4 a0, a1, a2, a3, a4, a5, b0, b1, b2, b3, b4, b5, e0, e1, e2, e3, e4, e5;
            ld6_nw(fast, pA, a0, a1, a2, a3, a4, a5);
            ld6_nw(fast, pB, b0, b1, b2, b3, b4, b5);
            ld6_nw(fast, pC, e0, e1, e2, e3, e4, e5);
            WAIT_VM(18);   // drains exactly prev ci(24) + prev stores (in-order vmcnt)
            #pragma unroll
            for (int nt = 0; nt < 6; nt++)
                #pragma unroll
                for (int r = 0; r < 4; r++)
                    acc[nt][r] = vld ? __uint_as_float(cr[nt][r] << 16) : biasreg[nt];
            vld = issue_preload(it + 1);   // off the publish path
            // own-chunk MFMAs (LDS) cover exchange flight
            bf16x8 afo0 = *(const bf16x8*)&hlds[l15 * 104 + 0 * 32 + q4 * 8];
            bf16x8 afo1 = *(const bf16x8*)&hlds[l15 * 104 + 1 * 32 + q4 * 8];
            bf16x8 afo2 = *(const bf16x8*)&hlds[l15 * 104 + 2 * 32 + q4 * 8];
            #pragma unroll
            for (int nt = 0; nt < 6; nt++)
                acc[nt] = __builtin_amdgcn_mfma_f32_16x16x32_bf16(afo0, bfr[nt][0], acc[nt], 0, 0, 0);
            #pragma unroll
            for (int nt = 0; nt < 6; nt++)
                acc[nt] = __builtin_amdgcn_mfma_f32_16x16x32_bf16(afo1, bfr[nt][1], acc[nt], 0, 0, 0);
            #pragma unroll
            for (int nt = 0; nt < 6; nt++)
                acc[nt] = __builtin_amdgcn_mfma_f32_16x16x32_bf16(afo2, bfr[nt][2], acc[nt], 0, 0, 0);
            int tries;
            WAIT_VM(36);   // A done (18 exch + 24 ci outstanding max = 42)
            tries = 0;
            while (!__all(sum6(a0, a1, a2, a3, a4, a5) == want) && ++tries < MAX_RETRY)
                ld6_wt(fast, pA, a0, a1, a2, a3, a4, a5);
            {
                bf16x8 fA0 = packf(a0, a1), fA1 = packf(a2, a3), fA2 = packf(a4, a5);
                #pragma unroll
                for (int nt = 0; nt < 6; nt++)
                    acc[nt] = __builtin_amdgcn_mfma_f32_16x16x32_bf16(fA0, bfr[nt][3], acc[nt], 0, 0, 0);
                #pragma unroll
                for (int nt = 0; nt < 6; nt++)
                    acc[nt] = __builtin_amdgcn_mfma_f32_16x16x32_bf16(fA1, bfr[nt][4], acc[nt], 0, 0, 0);
                #pragma unroll
                for (int nt = 0; nt < 6; nt++)
                    acc[nt] = __builtin_amdgcn_mfma_f32_16x16x32_bf16(fA2, bfr[nt][5], acc[nt], 0, 0, 0);
            }
            WAIT_VM(30);   // B done
            tries = 0;
            while (!__all(sum6(b0, b1, b2, b3, b4, b5) == want) && ++tries < MAX_RETRY)
                ld6_wt(fast, pB, b0, b1, b2, b3, b4, b5);
            {
                bf16x8 fB0 = packf(b0, b1), fB1 = packf(b2, b3), fB2 = packf(b4, b5);
                #pragma unroll
                for (int nt = 0; nt < 6; nt++)
                    acc[nt] = __builtin_amdgcn_mfma_f32_16x16x32_bf16(fB0, bfr[nt][6], acc[nt], 0, 0, 0);
                #pragma unroll
                for (int nt = 0; nt < 6; nt++)
                    acc[nt] = __builtin_amdgcn_mfma_f32_16x16x32_bf16(fB1, bfr[nt][7], acc[nt], 0, 0, 0);
                #pragma unroll
                for (int nt = 0; nt < 6; nt++)
                    acc[nt] = __builtin_amdgcn_mfma_f32_16x16x32_bf16(fB2, bfr[nt][8], acc[nt], 0, 0, 0);
            }
            WAIT_VM(24);   // C done (leaves the 24 ci in flight)
            tries = 0;
            while (!__all(sum6(e0, e1, e2, e3, e4, e5) == want) && ++tries < MAX_RETRY)
                ld6_wt(fast, pC, e0, e1, e2, e3, e4, e5);
            {
                bf16x8 fC0 = packf(e0, e1), fC1 = packf(e2, e3), fC2 = packf(e4, e5);
                #pragma unroll
                for (int nt = 0; nt < 6; nt++)
                    acc[nt] = __builtin_amdgcn_mfma_f32_16x16x32_bf16(fC0, bfr[nt][9], acc[nt], 0, 0, 0);
                #pragma unroll
                for (int nt = 0; nt < 6; nt++)
                    acc[nt] = __builtin_amdgcn_mfma_f32_16x16x32_bf16(fC1, bfr[nt][10], acc[nt], 0, 0, 0);
                #pragma unroll
                for (int nt = 0; nt < 6; nt++)
                    acc[nt] = __builtin_amdgcn_mfma_f32_16x16x32_bf16(fC2, bfr[nt][11], acc[nt], 0, 0, 0);
            }
        }

        // preact (this wave's gate) -> LDS (stride 100: bank-spread)
        #pragma unroll
        for (int nt = 0; nt < 6; nt++)
            #pragma unroll
            for (int r = 0; r < 4; r++)
                preact[w][(q4 * 4 + r) * 100 + nt * 16 + l15] = acc[nt][r];
        ldsbar();

        // cell update: 192 threads x 8 contiguous elements
        if (tid < 192) {
            int idx = bb * 100 + j0;
            u16* ho = hout + (((size_t)(d * NB + g * 16 + bb)) * NS + s) * NH + qc * 96 + j0;
            union { u16 u[8]; u32x4 v4; } pk;
            #pragma unroll
            for (int e = 0; e < 8; e++) {
                float gi = preact[0][idx + e], gf = preact[1][idx + e];
                float gg = preact[2][idx + e], go = preact[3][idx + e];
                float c = cre[e];
                float cn = sigm(gf) * c + sigm(gi) * tanh_(gg);
                float hn = sigm(go) * tanh_(cn);
                cre[e] = cn;
                pk.u[e] = f2b(hn);
            }
            u32 t2 = (u32)it + 1u;
            u32x4 lo, hi;
            lo[0] = ((u32)pk.u[0] << 16) | t2; lo[1] = ((u32)pk.u[1] << 16) | t2;
            lo[2] = ((u32)pk.u[2] << 16) | t2; lo[3] = ((u32)pk.u[3] << 16) | t2;
            hi[0] = ((u32)pk.u[4] << 16) | t2; hi[1] = ((u32)pk.u[5] << 16) | t2;
            hi[2] = ((u32)pk.u[6] << 16) | t2; hi[3] = ((u32)pk.u[7] << 16) | t2;
            u32* xp = xch + (((size_t)(t2 & 3u) * 8 + cl) * 16 + bb) * 384 + qc * 96 + j0;
            st8(fast, xp, lo, hi);                     // tagged publish FIRST
            *(u32x4*)ho = pk.v4;                       // output history (plain, cached)
            *(u32x4*)&hlds[bb * 104 + j0] = pk.v4;     // own chunk for next step
        }
        ldsbar();   // lgkm-only: no vm drain (R2-best)
    }
}

// ---------------- final linear: out[b,t,22] = [hf|hb] @ WlinT + blin ----------------
__global__ void k_final(const u16* __restrict__ hout, const float* __restrict__ wlin,
                        const float* __restrict__ blin, float* __restrict__ out) {
    int r = blockIdx.x * 256 + threadIdx.x;   // 0..32767
    int b = r >> 9, t = r & 511;
    const u16* hf = hout + ((size_t)b * NS + t) * NH;
    const u16* hb = hout + ((size_t)(NB + b) * NS + t) * NH;
    float acc[NT_OUT];
    #pragma unroll
    for (int tt = 0; tt < NT_OUT; tt++) acc[tt] = blin[tt];
    #pragma unroll 1
    for (int half = 0; half < 2; half++) {
        const u16* hp = half ? hb : hf;
        #pragma unroll 1
        for (int k8 = 0; k8 < NH / 8; k8++) {
            uint4 pk = *(const uint4*)(hp + k8 * 8);
            float x[8];
            x[0] = __uint_as_float(pk.x << 16); x[1] = __uint_as_float(pk.x & 0xffff0000u);
            x[2] = __uint_as_float(pk.y << 16); x[3] = __uint_as_float(pk.y & 0xffff0000u);
            x[4] = __uint_as_float(pk.z << 16); x[5] = __uint_as_float(pk.z & 0xffff0000u);
            x[6] = __uint_as_float(pk.w << 16); x[7] = __uint_as_float(pk.w & 0xffff0000u);
            int kk = half * NH + k8 * 8;
            #pragma unroll
            for (int e = 0; e < 8; e++)
                #pragma unroll
                for (int tt = 0; tt < NT_OUT; tt++)
                    acc[tt] += x[e] * wlin[tt * (2 * NH) + kk + e];   // uniform -> s_load
        }
    }
    float* op = out + (size_t)r * NT_OUT;
    #pragma unroll
    for (int tt = 0; tt < NT_OUT; tt++) op[tt] = acc[tt];
}

extern "C" void kernel_launch(void* const* d_in, const int* in_sizes, int n_in,
                              void* d_out, int out_size, void* d_ws, size_t ws_size,
                              hipStream_t stream) {
    const float* hidden = (const float*)d_in[0];
    const float* h0     = (const float*)d_in[1];
    const float* c0     = (const float*)d_in[2];
    const float* Wihf   = (const float*)d_in[3];
    const float* Whhf   = (const float*)d_in[4];
    const float* bihf   = (const float*)d_in[5];
    const float* bhhf   = (const float*)d_in[6];
    const float* Wihb   = (const float*)d_in[7];
    const float* Whhb   = (const float*)d_in[8];
    const float* bihb   = (const float*)d_in[9];
    const float* bhhb   = (const float*)d_in[10];
    const float* Wlin   = (const float*)d_in[11];
    const float* blin   = (const float*)d_in[12];
    const int* start_ids = (const int*)d_in[13];
    const int* masks     = (const int*)d_in[14];
    float* out = (float*)d_out;

    char* ws = (char*)d_ws;
    size_t off = 0;
    auto alloc = [&](size_t bytes) { void* p = ws + off; off += (bytes + 255) & ~(size_t)255; return p; };
    u16* embeds   = (u16*)alloc((size_t)MGEMM * ND * 2);           // 26.7 MB
    u16* wihcat   = (u16*)alloc((size_t)2 * NG * ND * 2);          // 4.7 MB
    float* biascat = (float*)alloc((size_t)2 * NG * 4);            // 12 KB
    u16* whhpack  = (u16*)alloc((size_t)2 * NG * NH * 2);          // 2.36 MB
    u16* h0buf    = (u16*)alloc((size_t)2 * NB * NH * 2);          // 98 KB
    u16* xg       = (u16*)alloc((size_t)2 * NB * S2 * NG * 2);     // 107 MB
    u16* hout     = (u16*)alloc((size_t)2 * NB * NS * NH * 2);     // 50.3 MB
    int* flags    = (int*)alloc((size_t)8 * NS * 4);               // 16 KB (probe+consensus)
    u32* xch      = (u32*)alloc((size_t)4 * 8 * 16 * 384 * 4);     // 768 KB tagged h exchange

    (void)hipMemsetAsync(flags, 0, (size_t)8 * NS * 4, stream);
    (void)hipMemsetAsync(xch, 0, (size_t)4 * 8 * 16 * 384 * 4, stream);
    k_prep<<<256, 256, 0, stream>>>(hidden, start_ids, masks, embeds);
    k_weights<<<512, 256, 0, stream>>>(Wihf, Wihb, bihf, bhhf, bihb, bhhb, h0,
                                       wihcat, biascat, h0buf);
    k_packwhh<<<576, 256, 0, stream>>>(Whhf, Whhb, whhpack);
    dim3 ggrid(2 * NG / 128, MGEMM / 128);
    k_gemm<<<ggrid, 256, 0, stream>>>(embeds, wihcat, biascat, xg);
    k_recur<<<32, 256, 0, stream>>>(whhpack, xg, biascat, h0buf, c0, hout, flags, xch);
    k_final<<<128, 256, 0, stream>>>(hout, Wlin, blin, out);
}

// Round 10
// 2729.131 us; speedup vs baseline: 1.1779x; 1.0606x over previous
//
#include <hip/hip_runtime.h>

typedef unsigned short u16;
typedef unsigned int u32;
typedef unsigned long long u64;

typedef short bf16x8 __attribute__((ext_vector_type(8)));
typedef float f32x4 __attribute__((ext_vector_type(4)));
typedef u32 u32x4 __attribute__((ext_vector_type(4)));
typedef u32 u32x2 __attribute__((ext_vector_type(2)));

#define NB 64
#define NS 512
#define ND 768
#define NH 384
#define NT_OUT 22
#define S2 272           // materialized xg time extent (n[b] <= 256 < 272)
#define NG 1536          // 4*H
#define MGEMM (NB*S2)    // 17408
#define MAGIC 0x5A5AA5A5u
#define MAX_RETRY 1000000  // watchdog: visibility failure -> wrong answer, never a hang

__device__ __forceinline__ u16 f2b(float f) {
    u32 u = __float_as_uint(f);
    u32 r = (u + 0x7fffu + ((u >> 16) & 1u)) >> 16;
    return (u16)r;
}
__device__ __forceinline__ float b2f(u16 s) { return __uint_as_float(((u32)s) << 16); }

__device__ __forceinline__ float sigm(float x) {
    return __builtin_amdgcn_rcpf(1.f + __expf(-x));
}
__device__ __forceinline__ float tanh_(float x) {
    return 1.f - 2.f * __builtin_amdgcn_rcpf(1.f + __expf(2.f * x));
}

__device__ __forceinline__ void gl_lds16(const void* g, void* l) {
    __builtin_amdgcn_global_load_lds(
        (const __attribute__((address_space(1))) unsigned int*)g,
        (__attribute__((address_space(3))) unsigned int*)l, 16, 0, 0);
}

// ---------------- exchange access helpers ----------------
// HW LESSON (R2 vs R4 A/B): plain global_load with sc0/sc1 can hit a STALE L1 line
// on gfx950 — a spinning poll never sees the remote write. `nt` (no L1 allocate) is
// what makes re-loads observe fresh L2 data.
// vmcnt LESSON (R9 failure): vmcnt completes IN ORDER; a retry's newest loads are
// only guaranteed complete at vmcnt(0). => polls/retries must run with ONLY L2
// exchange loads outstanding; long-latency (L3 ci) loads are issued AFTER the polls.
__device__ __forceinline__ u32 ld_sc0(const int* p) {
    u32 v;
    asm volatile("global_load_dword %0, %1, off sc0 nt\n\t"
                 "s_waitcnt vmcnt(0)"
                 : "=&v"(v) : "v"(p) : "memory");
    return v;
}
__device__ __forceinline__ void st_sc0(int* p, u32 v) {
    asm volatile("global_store_dword %0, %1, off sc0" :: "v"(p), "v"(v) : "memory");
}

// 6x dwordx4 of one sibling h-chunk (per lane: 3 k-slices x 8 tagged words), no wait
__device__ __forceinline__ void ld6_fast_nw(const u32* p,
        u32x4& A, u32x4& B, u32x4& C, u32x4& D, u32x4& E, u32x4& F) {
    asm volatile(
        "global_load_dwordx4 %0, %6, off sc0 nt\n\t"
        "global_load_dwordx4 %1, %6, off offset:16 sc0 nt\n\t"
        "global_load_dwordx4 %2, %6, off offset:128 sc0 nt\n\t"
        "global_load_dwordx4 %3, %6, off offset:144 sc0 nt\n\t"
        "global_load_dwordx4 %4, %6, off offset:256 sc0 nt\n\t"
        "global_load_dwordx4 %5, %6, off offset:272 sc0 nt"
        : "=&v"(A), "=&v"(B), "=&v"(C), "=&v"(D), "=&v"(E), "=&v"(F)
        : "v"(p) : "memory");
}
// retry path: internal vmcnt(0) — correct (in-order vmcnt) and cheap, because at
// poll time only L2 exchange loads are outstanding.
__device__ __forceinline__ void ld6_fast_wt(const u32* p,
        u32x4& A, u32x4& B, u32x4& C, u32x4& D, u32x4& E, u32x4& F) {
    asm volatile(
        "global_load_dwordx4 %0, %6, off sc0 nt\n\t"
        "global_load_dwordx4 %1, %6, off offset:16 sc0 nt\n\t"
        "global_load_dwordx4 %2, %6, off offset:128 sc0 nt\n\t"
        "global_load_dwordx4 %3, %6, off offset:144 sc0 nt\n\t"
        "global_load_dwordx4 %4, %6, off offset:256 sc0 nt\n\t"
        "global_load_dwordx4 %5, %6, off offset:272 sc0 nt\n\t"
        "s_waitcnt vmcnt(0)"
        : "=&v"(A), "=&v"(B), "=&v"(C), "=&v"(D), "=&v"(E), "=&v"(F)
        : "v"(p) : "memory");
}
// slow path: correctness-guaranteed AGENT atomics (blocking; fallback only)
__device__ __forceinline__ void ld6_slow(const u32* p,
        u32x4& A, u32x4& B, u32x4& C, u32x4& D, u32x4& E, u32x4& F) {
    #pragma unroll
    for (int e = 0; e < 4; e++) {
        A[e] = __hip_atomic_load(p + e,      __ATOMIC_RELAXED, __HIP_MEMORY_SCOPE_AGENT);
        B[e] = __hip_atomic_load(p + 4 + e,  __ATOMIC_RELAXED, __HIP_MEMORY_SCOPE_AGENT);
        C[e] = __hip_atomic_load(p + 32 + e, __ATOMIC_RELAXED, __HIP_MEMORY_SCOPE_AGENT);
        D[e] = __hip_atomic_load(p + 36 + e, __ATOMIC_RELAXED, __HIP_MEMORY_SCOPE_AGENT);
        E[e] = __hip_atomic_load(p + 64 + e, __ATOMIC_RELAXED, __HIP_MEMORY_SCOPE_AGENT);
        F[e] = __hip_atomic_load(p + 68 + e, __ATOMIC_RELAXED, __HIP_MEMORY_SCOPE_AGENT);
    }
}
__device__ __forceinline__ void ld6_nw(bool fast, const u32* p,
        u32x4& A, u32x4& B, u32x4& C, u32x4& D, u32x4& E, u32x4& F) {
    if (fast) ld6_fast_nw(p, A, B, C, D, E, F);
    else      ld6_slow(p, A, B, C, D, E, F);
}
__device__ __forceinline__ void ld6_wt(bool fast, const u32* p,
        u32x4& A, u32x4& B, u32x4& C, u32x4& D, u32x4& E, u32x4& F) {
    if (fast) ld6_fast_wt(p, A, B, C, D, E, F);
    else      ld6_slow(p, A, B, C, D, E, F);
}
#define WAIT_VM(N) do { __builtin_amdgcn_sched_barrier(0); \
    asm volatile("s_waitcnt vmcnt(" #N ")" ::: "memory"); \
    __builtin_amdgcn_sched_barrier(0); } while (0)
// LDS-only barrier (global exchange is self-validating; no vm drain)
__device__ __forceinline__ void ldsbar() {
    asm volatile("s_waitcnt lgkmcnt(0)" ::: "memory");
    __builtin_amdgcn_s_barrier();
    __builtin_amdgcn_sched_barrier(0);
}

// sum of low-16 tags of 24 words; tags monotone (stale in {0, T-4}) so
// sum == 24*T  <=>  all 24 words carry tag T.
__device__ __forceinline__ u32 sum6(const u32x4& a, const u32x4& b, const u32x4& c,
                                    const u32x4& d, const u32x4& e, const u32x4& f) {
    u32 s = (a[0] & 0xffffu) + (a[1] & 0xffffu) + (a[2] & 0xffffu) + (a[3] & 0xffffu);
    s += (b[0] & 0xffffu) + (b[1] & 0xffffu) + (b[2] & 0xffffu) + (b[3] & 0xffffu);
    s += (c[0] & 0xffffu) + (c[1] & 0xffffu) + (c[2] & 0xffffu) + (c[3] & 0xffffu);
    s += (d[0] & 0xffffu) + (d[1] & 0xffffu) + (d[2] & 0xffffu) + (d[3] & 0xffffu);
    s += (e[0] & 0xffffu) + (e[1] & 0xffffu) + (e[2] & 0xffffu) + (e[3] & 0xffffu);
    s += (f[0] & 0xffffu) + (f[1] & 0xffffu) + (f[2] & 0xffffu) + (f[3] & 0xffffu);
    return s;
}
// pack 8 tagged words (h in high 16 bits) -> bf16x8 fragment
__device__ __forceinline__ bf16x8 packf(const u32x4& lo, const u32x4& hi) {
    union { u32 q[4]; bf16x8 v; } U;
    U.q[0] = __builtin_amdgcn_perm(lo[1], lo[0], 0x07060302u);
    U.q[1] = __builtin_amdgcn_perm(lo[3], lo[2], 0x07060302u);
    U.q[2] = __builtin_amdgcn_perm(hi[1], hi[0], 0x07060302u);
    U.q[3] = __builtin_amdgcn_perm(hi[3], hi[2], 0x07060302u);
    return U.v;
}

// ---------------- prep: align/gather -> embeds bf16 [64][272][768] ----------------
__global__ void k_prep(const float* __restrict__ hidden, const int* __restrict__ start_ids,
                       const int* __restrict__ masks, u16* __restrict__ embeds) {
    int b = blockIdx.x >> 2;
    int quarter = blockIdx.x & 3;
    int tid = threadIdx.x;
    __shared__ int red[256];
    int cn = 0, cm = 0;
    for (int s = tid; s < NS; s += 256) {
        cn += (start_ids[b * NS + s] >= 0) ? 1 : 0;
        cm += (masks[b * NS + s] != 0) ? 1 : 0;
    }
    red[tid] = cn + (cm << 16);
    __syncthreads();
    #pragma unroll
    for (int off = 128; off > 0; off >>= 1) {
        if (tid < off) red[tid] += red[tid + off];
        __syncthreads();
    }
    int n = red[0] & 0xffff;
    int slen = red[0] >> 16;
    n = min(max(n, 1), NS);
    int last = start_ids[b * NS + n - 1];
    for (int t = quarter * 68; t < quarter * 68 + 68; ++t) {
        int idx;
        if (t == 0) idx = 0;
        else if (t < n) idx = start_ids[b * NS + t] - 1;
        else if (t == n) idx = last;
        else idx = 0;
        idx = min(max(idx, 0), NS - 1);
        bool keep = t < slen;
        const float* src = hidden + ((size_t)b * NS + idx) * ND;
        u16* dst = embeds + ((size_t)b * S2 + t) * ND;
        if (tid < 192) {
            float4 v = keep ? *(const float4*)(src + tid * 4) : make_float4(0.f, 0.f, 0.f, 0.f);
            union { u16 u[4]; uint2 q; } pk;
            pk.u[0] = f2b(v.x); pk.u[1] = f2b(v.y); pk.u[2] = f2b(v.z); pk.u[3] = f2b(v.w);
            *(uint2*)(dst + tid * 4) = pk.q;
        }
    }
}

// ---------------- weights: cast W_ih (cat) to bf16, bias sums, h0 cast ----------------
__global__ void k_weights(const float* __restrict__ wf, const float* __restrict__ wb,
                          const float* __restrict__ bihf, const float* __restrict__ bhhf,
                          const float* __restrict__ bihb, const float* __restrict__ bhhb,
                          const float* __restrict__ h0,
                          u16* __restrict__ wihcat, float* __restrict__ biascat,
                          u16* __restrict__ h0buf) {
    int i0 = blockIdx.x * blockDim.x + threadIdx.x;
    int NTH = gridDim.x * blockDim.x;
    for (size_t i = i0; i < (size_t)2 * NG * ND; i += NTH) {
        size_t nrow = i / ND, k = i - nrow * ND;
        float v = (nrow < NG) ? wf[nrow * ND + k] : wb[(nrow - NG) * ND + k];
        wihcat[i] = f2b(v);
    }
    for (int i = i0; i < 2 * NG; i += NTH)
        biascat[i] = (i < NG) ? bihf[i] + bhhf[i] : bihb[i - NG] + bhhb[i - NG];
    for (int i = i0; i < 2 * NB * NH; i += NTH) h0buf[i] = f2b(h0[i]);
}

// ---------------- pack Whh into MFMA B-fragment order ----------------
// layout: [d][qc][w][nt][ks][lane][8]  (d:2, qc:4 j-chunk, w:4 gate, nt:6, ks:12)
__global__ void k_packwhh(const float* __restrict__ whhf, const float* __restrict__ whhb,
                          u16* __restrict__ pack) {
    int ft = blockIdx.x * 256 + threadIdx.x;
    if (ft >= 2 * 4 * 4 * 6 * 12 * 64) return;
    int lane = ft & 63;
    int grp = ft >> 6;
    int ks = grp % 12; grp /= 12;
    int nt = grp % 6;  grp /= 6;
    int w  = grp & 3;  grp >>= 2;
    int qc = grp & 3;
    int d  = grp >> 2;
    const float* W = d ? whhb : whhf;
    int col = w * NH + qc * 96 + nt * 16 + (lane & 15);
    int k0 = ks * 32 + (lane >> 4) * 8;
    u16* dst = pack + (size_t)ft * 8;
    #pragma unroll
    for (int e = 0; e < 8; e++) dst[e] = f2b(W[(size_t)col * NH + k0 + e]);
}

// ---------------- GEMM: xg[d][b][t<272][1536] (bf16) = embeds @ WihcatT + bias ----------------
__launch_bounds__(256, 2)
__global__ void k_gemm(const u16* __restrict__ A, const u16* __restrict__ Bw,
                       const float* __restrict__ biascat, u16* __restrict__ xg) {
    __shared__ u16 As[128 * 32];
    __shared__ u16 Bs[128 * 32];
    int tid = threadIdx.x;
    int lane = tid & 63, wid = tid >> 6;
    int l15 = lane & 15, q4 = lane >> 4;
    int bn = blockIdx.x;   // 24 tiles of N=3072
    int bm = blockIdx.y;   // 136 tiles of M=17408
    int wm = (wid >> 1) * 64, wn = (wid & 1) * 64;
    f32x4 acc[4][4] = {};
    for (int k0 = 0; k0 < ND; k0 += 32) {
        #pragma unroll
        for (int j = 0; j < 2; j++) {
            int fl = tid + j * 256;
            int row = fl >> 2, cb = fl & 3;
            const u16* ga = A + (size_t)(bm * 128 + row) * ND + k0 + cb * 8;
            gl_lds16(ga, &As[(size_t)(wid * 64 + j * 256) * 8]);
            const u16* gb = Bw + (size_t)(bn * 128 + row) * ND + k0 + cb * 8;
            gl_lds16(gb, &Bs[(size_t)(wid * 64 + j * 256) * 8]);
        }
        __syncthreads();
        bf16x8 af[4], bf[4];
        #pragma unroll
        for (int mt = 0; mt < 4; mt++)
            af[mt] = *(const bf16x8*)&As[(wm + mt * 16 + l15) * 32 + q4 * 8];
        #pragma unroll
        for (int nt = 0; nt < 4; nt++)
            bf[nt] = *(const bf16x8*)&Bs[(wn + nt * 16 + l15) * 32 + q4 * 8];
        #pragma unroll
        for (int mt = 0; mt < 4; mt++)
            #pragma unroll
            for (int nt = 0; nt < 4; nt++)
                acc[mt][nt] = __builtin_amdgcn_mfma_f32_16x16x32_bf16(af[mt], bf[nt], acc[mt][nt], 0, 0, 0);
        __syncthreads();
    }
    #pragma unroll
    for (int nt = 0; nt < 4; nt++) {
        int gn = bn * 128 + wn + nt * 16 + l15;
        int d = gn >= NG ? 1 : 0;
        int col = gn - d * NG;
        float bias = biascat[gn];
        #pragma unroll
        for (int mt = 0; mt < 4; mt++) {
            #pragma unroll
            for (int r = 0; r < 4; r++) {
                int m = bm * 128 + wm + mt * 16 + q4 * 4 + r;
                int b = m / S2, t = m - b * S2;
                float v = acc[mt][nt][r] + bias;
                xg[((size_t)(d * NB + b) * S2 + t) * NG + col] = f2b(v);
            }
        }
    }
}

// ---------------- recurrence ----------------
// 32 WGs; cluster = (dir, batch-group) of 4 j-chunk WGs (blk%8 -> same-XCD heuristic).
// R10 = R9 with the vmcnt protocol made CORRECT and CHEAP simultaneously:
//  - ci(t+1) issued AFTER the last poll (R2 ordering): during polls only L2
//    exchange loads are outstanding.
//  - retries end in vmcnt(0) (ld6_wt) — the only correct wait for newest loads
//    (R9's counted retry waited on the WRONG loads); cost = one L2 RT.
//  - asm-ci ledger keeps the compiler from draining L3 ci on the publish path:
//    ci(24)+cell stores(6) drain at next step's WAIT_VM(18), before acc-init,
//    hidden under cell+barrier+exchange-issue.
// Ledger/step: [issue 18 exch] WAIT(18) -> acc init -> own MFMAs -> WAIT(12) poll A
// -> WAIT(6) poll B -> WAIT(0) poll C -> issue ci(t+1) -> preact -> bar -> cell
// (3x dwordx2 publish + 3x dword hout) -> bar.
__launch_bounds__(256, 1)
__global__ void k_recur(const u16* __restrict__ whhpack, const u16* __restrict__ xg,
                        const float* __restrict__ biascat, const u16* __restrict__ h0buf,
                        const float* __restrict__ c0, u16* __restrict__ hout,
                        int* __restrict__ flags, u32* __restrict__ xch) {
    const int blk = blockIdx.x;      // 0..31
    const int qc = blk >> 3;         // j-chunk 0..3
    const int cl = blk & 7;          // cluster id
    const int d = cl >> 2;           // direction
    const int g = cl & 3;            // batch group (16 batches)
    const int tid = threadIdx.x, lane = tid & 63, w = tid >> 6;  // wave = gate i,f,g,o
    const int q4 = lane >> 4, l15 = lane & 15;

    __shared__ float preact[4][16 * 100];  // pad 96->100 (R8: conflicts halved)
    __shared__ u16 hlds[16 * 104];         // own h chunk, padded stride 104
    __shared__ int s_fast;

    // stationary Whh B-fragments, SIBLING-PERMUTED ks order: j=0..2 own chunk,
    // 3..5 sib(qc+1), 6..8 sib(qc+2), 9..11 sib(qc+3).
    bf16x8 bfr[6][12];
    #pragma unroll
    for (int nt = 0; nt < 6; nt++)
        #pragma unroll
        for (int j = 0; j < 12; j++) {
            int ksg = ((qc + (j / 3)) & 3) * 3 + (j % 3);
            bfr[nt][j] = *(const bf16x8*)(whhpack +
                ((size_t)((((d * 4 + qc) * 4 + w) * 6 + nt) * 12 + ksg) * 64 + lane) * 8);
        }

    // c-state: ALL 256 threads x 6 contiguous j-elements (16 thr/batch)
    const int bb = tid >> 4;              // batch within group
    const int jo = (tid & 15) * 6;        // j offset within 96-chunk (even)
    float cre[6];
    {
        const float* cp = c0 + (size_t)(d * NB + g * 16 + bb) * NH + qc * 96 + jo;
        #pragma unroll
        for (int e = 0; e < 6; e++) cre[e] = cp[e];
    }
    float biasreg[6];
    #pragma unroll
    for (int nt = 0; nt < 6; nt++)
        biasreg[nt] = biascat[d * NG + w * NH + qc * 96 + nt * 16 + l15];

    // ---- co-location probe + consensus (once per launch) ----
    if (tid == 0) {
        int* pzb = flags + cl * 64;          // probe words, 64B-line spread
        int* pmb = flags + 2048 + cl * 64;   // consensus masks
        st_sc0(pzb + qc * 16, MAGIC);
        u32 seen = 1u << qc;
        for (int spin = 0; spin < 512 && seen != 0xFu; ++spin) {
            #pragma unroll
            for (int r = 0; r < 4; ++r)
                if (!((seen >> r) & 1u) && ld_sc0(pzb + r * 16) == MAGIC) seen |= 1u << r;
            __builtin_amdgcn_s_sleep(2);
        }
        __hip_atomic_store(pmb + qc * 16, (int)(0x100u | seen),
                           __ATOMIC_RELAXED, __HIP_MEMORY_SCOPE_AGENT);
        u32 m = 0xFu;
        int spin2 = 0;
        #pragma unroll
        for (int r = 0; r < 4; ++r) {
            u32 v;
            do {
                v = (u32)__hip_atomic_load(pmb + r * 16, __ATOMIC_RELAXED,
                                           __HIP_MEMORY_SCOPE_AGENT);
            } while (!(v & 0x100u) && ++spin2 < MAX_RETRY);
            m &= v;
        }
        s_fast = ((m & 0xFu) == 0xFu && spin2 < MAX_RETRY) ? 1 : 0;
    }
    __syncthreads();
    const bool fast = (s_fast != 0);

    const u16* xgd = xg + (size_t)d * NB * S2 * NG;

    // ci preload: 24 asm ushort loads (6 nt-cols x 4 batch-rows), counted in the
    // vmcnt ledger. Always issues (clamped row) so the ledger is constant.
    u32 cr[6][4];
    auto issue_preload = [&](int it2) -> bool {
        int s2 = d ? (NS - 1 - it2) : it2;
        bool ok = (s2 >= 0) && (s2 < S2);
        int s2c = min(max(s2, 0), S2 - 1);
        const u16* rp = xgd + ((size_t)(g * 16) * S2 + s2c) * NG + w * NH + qc * 96 + l15;
        #pragma unroll
        for (int r = 0; r < 4; r++) {
            const u16* base = rp + (size_t)(q4 * 4 + r) * S2 * NG;
            asm volatile(
                "global_load_ushort %0, %6, off\n\t"
                "global_load_ushort %1, %6, off offset:32\n\t"
                "global_load_ushort %2, %6, off offset:64\n\t"
                "global_load_ushort %3, %6, off offset:96\n\t"
                "global_load_ushort %4, %6, off offset:128\n\t"
                "global_load_ushort %5, %6, off offset:160"
                : "=&v"(cr[0][r]), "=&v"(cr[1][r]), "=&v"(cr[2][r]),
                  "=&v"(cr[3][r]), "=&v"(cr[4][r]), "=&v"(cr[5][r])
                : "v"(base) : "memory");
        }
        return ok;
    };
    bool vld = issue_preload(0);

    #pragma unroll 1
    for (int it = 0; it < NS; ++it) {
        int s = d ? (NS - 1 - it) : it;
        f32x4 acc[6];

        if (it == 0) {
            WAIT_VM(0);   // ci(0) ready
            #pragma unroll
            for (int nt = 0; nt < 6; nt++)
                #pragma unroll
                for (int r = 0; r < 4; r++)
                    acc[nt][r] = vld ? __uint_as_float(cr[nt][r] << 16) : biasreg[nt];
            vld = issue_preload(1);   // ci(1): 24 outstanding entering cell
            const u16* hp = h0buf + (size_t)(d * NB + g * 16) * NH;
            #pragma unroll
            for (int j = 0; j < 12; j++) {
                int ksg = ((qc + (j / 3)) & 3) * 3 + (j % 3);
                bf16x8 af = *(const bf16x8*)(hp + (size_t)l15 * NH + ksg * 32 + q4 * 8);
                #pragma unroll
                for (int nt = 0; nt < 6; nt++)
                    acc[nt] = __builtin_amdgcn_mfma_f32_16x16x32_bf16(af, bfr[nt][j], acc[nt], 0, 0, 0);
            }
        } else {
            const u32 T = (u32)it;
            const u32 want = T * 24u;
            u32* xrow = xch + (((size_t)(T & 3u) * 8 + cl) * 16 + l15) * 384 + q4 * 8;
            u32* pA = xrow + ((qc + 1) & 3) * 96;
            u32* pB = xrow + ((qc + 2) & 3) * 96;
            u32* pC = xrow + ((qc + 3) & 3) * 96;
            u32x4 a0, a1, a2, a3, a4, a5, b0, b1, b2, b3, b4, b5, e0, e1, e2, e3, e4, e5;
            // entering: ci(24) then stores(6) outstanding = 30; issue 18 exch -> 48
            ld6_nw(fast, pA, a0, a1, a2, a3, a4, a5);
            ld6_nw(fast, pB, b0, b1, b2, b3, b4, b5);
            ld6_nw(fast, pC, e0, e1, e2, e3, e4, e5);
            WAIT_VM(18);   // drains ci(24)+stores(6); leaves exactly the 18 exch
            #pragma unroll
            for (int nt = 0; nt < 6; nt++)
                #pragma unroll
                for (int r = 0; r < 4; r++)
                    acc[nt][r] = vld ? __uint_as_float(cr[nt][r] << 16) : biasreg[nt];
            // own-chunk MFMAs (LDS) cover exchange flight
            bf16x8 afo0 = *(const bf16x8*)&hlds[l15 * 104 + 0 * 32 + q4 * 8];
            bf16x8 afo1 = *(const bf16x8*)&hlds[l15 * 104 + 1 * 32 + q4 * 8];
            bf16x8 afo2 = *(const bf16x8*)&hlds[l15 * 104 + 2 * 32 + q4 * 8];
            #pragma unroll
            for (int nt = 0; nt < 6; nt++)
                acc[nt] = __builtin_amdgcn_mfma_f32_16x16x32_bf16(afo0, bfr[nt][0], acc[nt], 0, 0, 0);
            #pragma unroll
            for (int nt = 0; nt < 6; nt++)
                acc[nt] = __builtin_amdgcn_mfma_f32_16x16x32_bf16(afo1, bfr[nt][1], acc[nt], 0, 0, 0);
            #pragma unroll
            for (int nt = 0; nt < 6; nt++)
                acc[nt] = __builtin_amdgcn_mfma_f32_16x16x32_bf16(afo2, bfr[nt][2], acc[nt], 0, 0, 0);
            int tries;
            // chunk A: outstanding 18 -> WAIT(12) drains A's 6 (oldest)
            WAIT_VM(12);
            tries = 0;
            while (!__all(sum6(a0, a1, a2, a3, a4, a5) == want) && ++tries < MAX_RETRY)
                ld6_wt(fast, pA, a0, a1, a2, a3, a4, a5);   // vmcnt(0): L2-only queue
            {
                bf16x8 fA0 = packf(a0, a1), fA1 = packf(a2, a3), fA2 = packf(a4, a5);
                #pragma unroll
                for (int nt = 0; nt < 6; nt++)
                    acc[nt] = __builtin_amdgcn_mfma_f32_16x16x32_bf16(fA0, bfr[nt][3], acc[nt], 0, 0, 0);
                #pragma unroll
                for (int nt = 0; nt < 6; nt++)
                    acc[nt] = __builtin_amdgcn_mfma_f32_16x16x32_bf16(fA1, bfr[nt][4], acc[nt], 0, 0, 0);
                #pragma unroll
                for (int nt = 0; nt < 6; nt++)
                    acc[nt] = __builtin_amdgcn_mfma_f32_16x16x32_bf16(fA2, bfr[nt][5], acc[nt], 0, 0, 0);
            }
            // chunk B
            WAIT_VM(6);
            tries = 0;
            while (!__all(sum6(b0, b1, b2, b3, b4, b5) == want) && ++tries < MAX_RETRY)
                ld6_wt(fast, pB, b0, b1, b2, b3, b4, b5);
            {
                bf16x8 fB0 = packf(b0, b1), fB1 = packf(b2, b3), fB2 = packf(b4, b5);
                #pragma unroll
                for (int nt = 0; nt < 6; nt++)
                    acc[nt] = __builtin_amdgcn_mfma_f32_16x16x32_bf16(fB0, bfr[nt][6], acc[nt], 0, 0, 0);
                #pragma unroll
                for (int nt = 0; nt < 6; nt++)
                    acc[nt] = __builtin_amdgcn_mfma_f32_16x16x32_bf16(fB1, bfr[nt][7], acc[nt], 0, 0, 0);
                #pragma unroll
                for (int nt = 0; nt < 6; nt++)
                    acc[nt] = __builtin_amdgcn_mfma_f32_16x16x32_bf16(fB2, bfr[nt][8], acc[nt], 0, 0, 0);
            }
            // chunk C
            WAIT_VM(0);
            tries = 0;
            while (!__all(sum6(e0, e1, e2, e3, e4, e5) == want) && ++tries < MAX_RETRY)
                ld6_wt(fast, pC, e0, e1, e2, e3, e4, e5);
            vld = issue_preload(it + 1);   // ci AFTER polls: hides under cell+bar
            {
                bf16x8 fC0 = packf(e0, e1), fC1 = packf(e2, e3), fC2 = packf(e4, e5);
                #pragma unroll
                for (int nt = 0; nt < 6; nt++)
                    acc[nt] = __builtin_amdgcn_mfma_f32_16x16x32_bf16(fC0, bfr[nt][9], acc[nt], 0, 0, 0);
                #pragma unroll
                for (int nt = 0; nt < 6; nt++)
                    acc[nt] = __builtin_amdgcn_mfma_f32_16x16x32_bf16(fC1, bfr[nt][10], acc[nt], 0, 0, 0);
                #pragma unroll
                for (int nt = 0; nt < 6; nt++)
                    acc[nt] = __builtin_amdgcn_mfma_f32_16x16x32_bf16(fC2, bfr[nt][11], acc[nt], 0, 0, 0);
            }
        }

        // preact (this wave's gate) -> LDS (stride 100: bank-spread)
        #pragma unroll
        for (int nt = 0; nt < 6; nt++)
            #pragma unroll
            for (int r = 0; r < 4; r++)
                preact[w][(q4 * 4 + r) * 100 + nt * 16 + l15] = acc[nt][r];
        ldsbar();

        // cell update: ALL 256 threads x 6 contiguous elements
        {
            int idx = bb * 100 + jo;
            u16* ho = hout + (((size_t)(d * NB + g * 16 + bb)) * NS + s) * NH + qc * 96 + jo;
            union { u16 u[6]; u32 d3[3]; } pk;
            u32 t2 = (u32)it + 1u;
            #pragma unroll
            for (int e = 0; e < 6; e++) {
                float gi = preact[0][idx + e], gf = preact[1][idx + e];
                float gg = preact[2][idx + e], go = preact[3][idx + e];
                float c = cre[e];
                float cn = sigm(gf) * c + sigm(gi) * tanh_(gg);
                float hn = sigm(go) * tanh_(cn);
                cre[e] = cn;
                pk.u[e] = f2b(hn);
            }
            u32x2 s0, s1, s2;
            s0[0] = ((u32)pk.u[0] << 16) | t2; s0[1] = ((u32)pk.u[1] << 16) | t2;
            s1[0] = ((u32)pk.u[2] << 16) | t2; s1[1] = ((u32)pk.u[3] << 16) | t2;
            s2[0] = ((u32)pk.u[4] << 16) | t2; s2[1] = ((u32)pk.u[5] << 16) | t2;
            u32* xp = xch + (((size_t)(t2 & 3u) * 8 + cl) * 16 + bb) * 384 + qc * 96 + jo;
            if (fast)
                asm volatile(
                    "global_store_dwordx2 %0, %1, off sc0\n\t"
                    "global_store_dwordx2 %0, %2, off offset:8 sc0\n\t"
                    "global_store_dwordx2 %0, %3, off offset:16 sc0"
                    :: "v"(xp), "v"(s0), "v"(s1), "v"(s2) : "memory");
            else {
                __hip_atomic_store(xp,     s0[0], __ATOMIC_RELAXED, __HIP_MEMORY_SCOPE_AGENT);
                __hip_atomic_store(xp + 1, s0[1], __ATOMIC_RELAXED, __HIP_MEMORY_SCOPE_AGENT);
                __hip_atomic_store(xp + 2, s1[0], __ATOMIC_RELAXED, __HIP_MEMORY_SCOPE_AGENT);
                __hip_atomic_store(xp + 3, s1[1], __ATOMIC_RELAXED, __HIP_MEMORY_SCOPE_AGENT);
                __hip_atomic_store(xp + 4, s2[0], __ATOMIC_RELAXED, __HIP_MEMORY_SCOPE_AGENT);
                __hip_atomic_store(xp + 5, s2[1], __ATOMIC_RELAXED, __HIP_MEMORY_SCOPE_AGENT);
            }
            // output history (plain, cached) + own chunk in LDS
            *(u32*)(ho)     = pk.d3[0];
            *(u32*)(ho + 2) = pk.d3[1];
            *(u32*)(ho + 4) = pk.d3[2];
            u16* hl = &hlds[bb * 104 + jo];
            *(u32*)(hl)     = pk.d3[0];
            *(u32*)(hl + 2) = pk.d3[1];
            *(u32*)(hl + 4) = pk.d3[2];
        }
        ldsbar();   // lgkm-only: no vm drain
    }
}

// ---------------- final linear: out[b,t,22] = [hf|hb] @ WlinT + blin ----------------
__global__ void k_final(const u16* __restrict__ hout, const float* __restrict__ wlin,
                        const float* __restrict__ blin, float* __restrict__ out) {
    int r = blockIdx.x * 256 + threadIdx.x;   // 0..32767
    int b = r >> 9, t = r & 511;
    const u16* hf = hout + ((size_t)b * NS + t) * NH;
    const u16* hb = hout + ((size_t)(NB + b) * NS + t) * NH;
    float acc[NT_OUT];
    #pragma unroll
    for (int tt = 0; tt < NT_OUT; tt++) acc[tt] = blin[tt];
    #pragma unroll 1
    for (int half = 0; half < 2; half++) {
        const u16* hp = half ? hb : hf;
        #pragma unroll 1
        for (int k8 = 0; k8 < NH / 8; k8++) {
            uint4 pk = *(const uint4*)(hp + k8 * 8);
            float x[8];
            x[0] = __uint_as_float(pk.x << 16); x[1] = __uint_as_float(pk.x & 0xffff0000u);
            x[2] = __uint_as_float(pk.y << 16); x[3] = __uint_as_float(pk.y & 0xffff0000u);
            x[4] = __uint_as_float(pk.z << 16); x[5] = __uint_as_float(pk.z & 0xffff0000u);
            x[6] = __uint_as_float(pk.w << 16); x[7] = __uint_as_float(pk.w & 0xffff0000u);
            int kk = half * NH + k8 * 8;
            #pragma unroll
            for (int e = 0; e < 8; e++)
                #pragma unroll
                for (int tt = 0; tt < NT_OUT; tt++)
                    acc[tt] += x[e] * wlin[tt * (2 * NH) + kk + e];   // uniform -> s_load
        }
    }
    float* op = out + (size_t)r * NT_OUT;
    #pragma unroll
    for (int tt = 0; tt < NT_OUT; tt++) op[tt] = acc[tt];
}

extern "C" void kernel_launch(void* const* d_in, const int* in_sizes, int n_in,
                              void* d_out, int out_size, void* d_ws, size_t ws_size,
                              hipStream_t stream) {
    const float* hidden = (const float*)d_in[0];
    const float* h0     = (const float*)d_in[1];
    const float* c0     = (const float*)d_in[2];
    const float* Wihf   = (const float*)d_in[3];
    const float* Whhf   = (const float*)d_in[4];
    const float* bihf   = (const float*)d_in[5];
    const float* bhhf   = (const float*)d_in[6];
    const float* Wihb   = (const float*)d_in[7];
    const float* Whhb   = (const float*)d_in[8];
    const float* bihb   = (const float*)d_in[9];
    const float* bhhb   = (const float*)d_in[10];
    const float* Wlin   = (const float*)d_in[11];
    const float* blin   = (const float*)d_in[12];
    const int* start_ids = (const int*)d_in[13];
    const int* masks     = (const int*)d_in[14];
    float* out = (float*)d_out;

    char* ws = (char*)d_ws;
    size_t off = 0;
    auto alloc = [&](size_t bytes) { void* p = ws + off; off += (bytes + 255) & ~(size_t)255; return p; };
    u16* embeds   = (u16*)alloc((size_t)MGEMM * ND * 2);           // 26.7 MB
    u16* wihcat   = (u16*)alloc((size_t)2 * NG * ND * 2);          // 4.7 MB
    float* biascat = (float*)alloc((size_t)2 * NG * 4);            // 12 KB
    u16* whhpack  = (u16*)alloc((size_t)2 * NG * NH * 2);          // 2.36 MB
    u16* h0buf    = (u16*)alloc((size_t)2 * NB * NH * 2);          // 98 KB
    u16* xg       = (u16*)alloc((size_t)2 * NB * S2 * NG * 2);     // 107 MB
    u16* hout     = (u16*)alloc((size_t)2 * NB * NS * NH * 2);     // 50.3 MB
    int* flags    = (int*)alloc((size_t)8 * NS * 4);               // 16 KB (probe+consensus)
    u32* xch      = (u32*)alloc((size_t)4 * 8 * 16 * 384 * 4);     // 768 KB tagged h exchange

    (void)hipMemsetAsync(flags, 0, (size_t)8 * NS * 4, stream);
    (void)hipMemsetAsync(xch, 0, (size_t)4 * 8 * 16 * 384 * 4, stream);
    k_prep<<<256, 256, 0, stream>>>(hidden, start_ids, masks, embeds);
    k_weights<<<512, 256, 0, stream>>>(Wihf, Wihb, bihf, bhhf, bihb, bhhb, h0,
                                       wihcat, biascat, h0buf);
    k_packwhh<<<576, 256, 0, stream>>>(Whhf, Whhb, whhpack);
    dim3 ggrid(2 * NG / 128, MGEMM / 128);
    k_gemm<<<ggrid, 256, 0, stream>>>(embeds, wihcat, biascat, xg);
    k_recur<<<32, 256, 0, stream>>>(whhpack, xg, biascat, h0buf, c0, hout, flags, xch);
    k_final<<<128, 256, 0, stream>>>(hout, Wlin, blin, out);
}

// Round 11
// 2567.748 us; speedup vs baseline: 1.2519x; 1.0628x over previous
//
#include <hip/hip_runtime.h>

typedef unsigned short u16;
typedef unsigned int u32;
typedef unsigned long long u64;

typedef short bf16x8 __attribute__((ext_vector_type(8)));
typedef float f32x4 __attribute__((ext_vector_type(4)));
typedef u32 u32x4 __attribute__((ext_vector_type(4)));

#define NB 64
#define NS 512
#define ND 768
#define NH 384
#define NT_OUT 22
#define S2 272           // materialized xg time extent (n[b] <= 256 < 272)
#define NG 1536          // 4*H
#define MGEMM (NB*S2)    // 17408
#define MAGIC 0x5A5AA5A5u
#define MAX_RETRY 1000000  // watchdog: visibility failure -> wrong answer, never a hang
#define NQC 6              // j-chunks per cluster (64 j each)

__device__ __forceinline__ u16 f2b(float f) {
    u32 u = __float_as_uint(f);
    u32 r = (u + 0x7fffu + ((u >> 16) & 1u)) >> 16;
    return (u16)r;
}
__device__ __forceinline__ float b2f(u16 s) { return __uint_as_float(((u32)s) << 16); }

__device__ __forceinline__ float sigm(float x) {
    return __builtin_amdgcn_rcpf(1.f + __expf(-x));
}
__device__ __forceinline__ float tanh_(float x) {
    return 1.f - 2.f * __builtin_amdgcn_rcpf(1.f + __expf(2.f * x));
}

__device__ __forceinline__ void gl_lds16(const void* g, void* l) {
    __builtin_amdgcn_global_load_lds(
        (const __attribute__((address_space(1))) unsigned int*)g,
        (__attribute__((address_space(3))) unsigned int*)l, 16, 0, 0);
}

// ---------------- exchange access helpers ----------------
// HW LESSON (R2 vs R4 A/B): plain global_load with sc0/sc1 can hit a STALE L1 line
// on gfx950. `nt` (no L1 allocate) makes re-loads observe fresh L2 data.
// vmcnt LESSON (R9): vmcnt completes IN ORDER; retry loads are the NEWEST ops and
// are only guaranteed complete at vmcnt(0) -> polls must run with an L2-only queue.
__device__ __forceinline__ u32 ld_sc0(const int* p) {
    u32 v;
    asm volatile("global_load_dword %0, %1, off sc0 nt\n\t"
                 "s_waitcnt vmcnt(0)"
                 : "=&v"(v) : "v"(p) : "memory");
    return v;
}
__device__ __forceinline__ void st_sc0(int* p, u32 v) {
    asm volatile("global_store_dword %0, %1, off sc0" :: "v"(p), "v"(v) : "memory");
}

// one chunk (64 j = 2 k-slices): 4x dwordx4 of tagged words, no wait
__device__ __forceinline__ void ld4_fast_nw(const u32* p,
        u32x4& A, u32x4& B, u32x4& C, u32x4& D) {
    asm volatile(
        "global_load_dwordx4 %0, %4, off sc0 nt\n\t"
        "global_load_dwordx4 %1, %4, off offset:16 sc0 nt\n\t"
        "global_load_dwordx4 %2, %4, off offset:128 sc0 nt\n\t"
        "global_load_dwordx4 %3, %4, off offset:144 sc0 nt"
        : "=&v"(A), "=&v"(B), "=&v"(C), "=&v"(D)
        : "v"(p) : "memory");
}
__device__ __forceinline__ void ld4_fast_wt(const u32* p,
        u32x4& A, u32x4& B, u32x4& C, u32x4& D) {
    asm volatile(
        "global_load_dwordx4 %0, %4, off sc0 nt\n\t"
        "global_load_dwordx4 %1, %4, off offset:16 sc0 nt\n\t"
        "global_load_dwordx4 %2, %4, off offset:128 sc0 nt\n\t"
        "global_load_dwordx4 %3, %4, off offset:144 sc0 nt\n\t"
        "s_waitcnt vmcnt(0)"
        : "=&v"(A), "=&v"(B), "=&v"(C), "=&v"(D)
        : "v"(p) : "memory");
}
__device__ __forceinline__ void ld4_slow(const u32* p,
        u32x4& A, u32x4& B, u32x4& C, u32x4& D) {
    #pragma unroll
    for (int e = 0; e < 4; e++) {
        A[e] = __hip_atomic_load(p + e,      __ATOMIC_RELAXED, __HIP_MEMORY_SCOPE_AGENT);
        B[e] = __hip_atomic_load(p + 4 + e,  __ATOMIC_RELAXED, __HIP_MEMORY_SCOPE_AGENT);
        C[e] = __hip_atomic_load(p + 32 + e, __ATOMIC_RELAXED, __HIP_MEMORY_SCOPE_AGENT);
        D[e] = __hip_atomic_load(p + 36 + e, __ATOMIC_RELAXED, __HIP_MEMORY_SCOPE_AGENT);
    }
}
__device__ __forceinline__ void ld4_nw(bool fast, const u32* p,
        u32x4& A, u32x4& B, u32x4& C, u32x4& D) {
    if (fast) ld4_fast_nw(p, A, B, C, D);
    else      ld4_slow(p, A, B, C, D);
}
__device__ __forceinline__ void ld4_wt(bool fast, const u32* p,
        u32x4& A, u32x4& B, u32x4& C, u32x4& D) {
    if (fast) ld4_fast_wt(p, A, B, C, D);
    else      ld4_slow(p, A, B, C, D);
}
#define WAIT_VM(N) do { __builtin_amdgcn_sched_barrier(0); \
    asm volatile("s_waitcnt vmcnt(" #N ")" ::: "memory"); \
    __builtin_amdgcn_sched_barrier(0); } while (0)
// LDS-only barrier (global exchange is self-validating; no vm drain)
__device__ __forceinline__ void ldsbar() {
    asm volatile("s_waitcnt lgkmcnt(0)" ::: "memory");
    __builtin_amdgcn_s_barrier();
    __builtin_amdgcn_sched_barrier(0);
}

// sum of low-16 tags of 16 words; tags monotone (stale in {0, T-4}) so
// sum == 16*T  <=>  all 16 words carry tag T.
__device__ __forceinline__ u32 sum4(const u32x4& a, const u32x4& b,
                                    const u32x4& c, const u32x4& d) {
    u32 s = (a[0] & 0xffffu) + (a[1] & 0xffffu) + (a[2] & 0xffffu) + (a[3] & 0xffffu);
    s += (b[0] & 0xffffu) + (b[1] & 0xffffu) + (b[2] & 0xffffu) + (b[3] & 0xffffu);
    s += (c[0] & 0xffffu) + (c[1] & 0xffffu) + (c[2] & 0xffffu) + (c[3] & 0xffffu);
    s += (d[0] & 0xffffu) + (d[1] & 0xffffu) + (d[2] & 0xffffu) + (d[3] & 0xffffu);
    return s;
}
// pack 8 tagged words (h in high 16 bits) -> bf16x8 fragment
__device__ __forceinline__ bf16x8 packf(const u32x4& lo, const u32x4& hi) {
    union { u32 q[4]; bf16x8 v; } U;
    U.q[0] = __builtin_amdgcn_perm(lo[1], lo[0], 0x07060302u);
    U.q[1] = __builtin_amdgcn_perm(lo[3], lo[2], 0x07060302u);
    U.q[2] = __builtin_amdgcn_perm(hi[1], hi[0], 0x07060302u);
    U.q[3] = __builtin_amdgcn_perm(hi[3], hi[2], 0x07060302u);
    return U.v;
}

// ---------------- prep: align/gather -> embeds bf16 [64][272][768] ----------------
__global__ void k_prep(const float* __restrict__ hidden, const int* __restrict__ start_ids,
                       const int* __restrict__ masks, u16* __restrict__ embeds) {
    int b = blockIdx.x >> 2;
    int quarter = blockIdx.x & 3;
    int tid = threadIdx.x;
    __shared__ int red[256];
    int cn = 0, cm = 0;
    for (int s = tid; s < NS; s += 256) {
        cn += (start_ids[b * NS + s] >= 0) ? 1 : 0;
        cm += (masks[b * NS + s] != 0) ? 1 : 0;
    }
    red[tid] = cn + (cm << 16);
    __syncthreads();
    #pragma unroll
    for (int off = 128; off > 0; off >>= 1) {
        if (tid < off) red[tid] += red[tid + off];
        __syncthreads();
    }
    int n = red[0] & 0xffff;
    int slen = red[0] >> 16;
    n = min(max(n, 1), NS);
    int last = start_ids[b * NS + n - 1];
    for (int t = quarter * 68; t < quarter * 68 + 68; ++t) {
        int idx;
        if (t == 0) idx = 0;
        else if (t < n) idx = start_ids[b * NS + t] - 1;
        else if (t == n) idx = last;
        else idx = 0;
        idx = min(max(idx, 0), NS - 1);
        bool keep = t < slen;
        const float* src = hidden + ((size_t)b * NS + idx) * ND;
        u16* dst = embeds + ((size_t)b * S2 + t) * ND;
        if (tid < 192) {
            float4 v = keep ? *(const float4*)(src + tid * 4) : make_float4(0.f, 0.f, 0.f, 0.f);
            union { u16 u[4]; uint2 q; } pk;
            pk.u[0] = f2b(v.x); pk.u[1] = f2b(v.y); pk.u[2] = f2b(v.z); pk.u[3] = f2b(v.w);
            *(uint2*)(dst + tid * 4) = pk.q;
        }
    }
}

// ---------------- weights: cast W_ih (cat) to bf16, bias sums, h0 cast ----------------
__global__ void k_weights(const float* __restrict__ wf, const float* __restrict__ wb,
                          const float* __restrict__ bihf, const float* __restrict__ bhhf,
                          const float* __restrict__ bihb, const float* __restrict__ bhhb,
                          const float* __restrict__ h0,
                          u16* __restrict__ wihcat, float* __restrict__ biascat,
                          u16* __restrict__ h0buf) {
    int i0 = blockIdx.x * blockDim.x + threadIdx.x;
    int NTH = gridDim.x * blockDim.x;
    for (size_t i = i0; i < (size_t)2 * NG * ND; i += NTH) {
        size_t nrow = i / ND, k = i - nrow * ND;
        float v = (nrow < NG) ? wf[nrow * ND + k] : wb[(nrow - NG) * ND + k];
        wihcat[i] = f2b(v);
    }
    for (int i = i0; i < 2 * NG; i += NTH)
        biascat[i] = (i < NG) ? bihf[i] + bhhf[i] : bihb[i - NG] + bhhb[i - NG];
    for (int i = i0; i < 2 * NB * NH; i += NTH) h0buf[i] = f2b(h0[i]);
}

// ---------------- pack Whh into MFMA B-fragment order (GATE-LOCAL) ----------------
// layout: [d][qc6][wj4][gate4][ks12][lane][8]
// (qc: 64-j chunk; wj: wave's 16-j tile; gate-local -> cell is register-local)
__global__ void k_packwhh(const float* __restrict__ whhf, const float* __restrict__ whhb,
                          u16* __restrict__ pack) {
    int ft = blockIdx.x * 256 + threadIdx.x;
    if (ft >= 2 * NQC * 4 * 4 * 12 * 64) return;
    int lane = ft & 63;
    int grp = ft >> 6;
    int ks = grp % 12; grp /= 12;
    int gate = grp & 3; grp >>= 2;
    int wj = grp & 3;  grp >>= 2;
    int qc = grp % NQC;
    int d  = grp / NQC;
    const float* W = d ? whhb : whhf;
    int col = gate * NH + qc * 64 + wj * 16 + (lane & 15);
    int k0 = ks * 32 + (lane >> 4) * 8;
    u16* dst = pack + (size_t)ft * 8;
    #pragma unroll
    for (int e = 0; e < 8; e++) dst[e] = f2b(W[(size_t)col * NH + k0 + e]);
}

// ---------------- GEMM: xg[d][b][t<272][1536] (bf16) = embeds @ WihcatT + bias ----------------
__launch_bounds__(256, 2)
__global__ void k_gemm(const u16* __restrict__ A, const u16* __restrict__ Bw,
                       const float* __restrict__ biascat, u16* __restrict__ xg) {
    __shared__ u16 As[128 * 32];
    __shared__ u16 Bs[128 * 32];
    int tid = threadIdx.x;
    int lane = tid & 63, wid = tid >> 6;
    int l15 = lane & 15, q4 = lane >> 4;
    int bn = blockIdx.x;   // 24 tiles of N=3072
    int bm = blockIdx.y;   // 136 tiles of M=17408
    int wm = (wid >> 1) * 64, wn = (wid & 1) * 64;
    f32x4 acc[4][4] = {};
    for (int k0 = 0; k0 < ND; k0 += 32) {
        #pragma unroll
        for (int j = 0; j < 2; j++) {
            int fl = tid + j * 256;
            int row = fl >> 2, cb = fl & 3;
            const u16* ga = A + (size_t)(bm * 128 + row) * ND + k0 + cb * 8;
            gl_lds16(ga, &As[(size_t)(wid * 64 + j * 256) * 8]);
            const u16* gb = Bw + (size_t)(bn * 128 + row) * ND + k0 + cb * 8;
            gl_lds16(gb, &Bs[(size_t)(wid * 64 + j * 256) * 8]);
        }
        __syncthreads();
        bf16x8 af[4], bf[4];
        #pragma unroll
        for (int mt = 0; mt < 4; mt++)
            af[mt] = *(const bf16x8*)&As[(wm + mt * 16 + l15) * 32 + q4 * 8];
        #pragma unroll
        for (int nt = 0; nt < 4; nt++)
            bf[nt] = *(const bf16x8*)&Bs[(wn + nt * 16 + l15) * 32 + q4 * 8];
        #pragma unroll
        for (int mt = 0; mt < 4; mt++)
            #pragma unroll
            for (int nt = 0; nt < 4; nt++)
                acc[mt][nt] = __builtin_amdgcn_mfma_f32_16x16x32_bf16(af[mt], bf[nt], acc[mt][nt], 0, 0, 0);
        __syncthreads();
    }
    #pragma unroll
    for (int nt = 0; nt < 4; nt++) {
        int gn = bn * 128 + wn + nt * 16 + l15;
        int d = gn >= NG ? 1 : 0;
        int col = gn - d * NG;
        float bias = biascat[gn];
        #pragma unroll
        for (int mt = 0; mt < 4; mt++) {
            #pragma unroll
            for (int r = 0; r < 4; r++) {
                int m = bm * 128 + wm + mt * 16 + q4 * 4 + r;
                int b = m / S2, t = m - b * S2;
                float v = acc[mt][nt][r] + bias;
                xg[((size_t)(d * NB + b) * S2 + t) * NG + col] = f2b(v);
            }
        }
    }
}

// ---------------- recurrence: 6-WG gate-local, register-local cell, 1 barrier ----------------
// 48 WGs; cluster = (dir, batch-group) of SIX 64-j WGs (blk%8 -> same-XCD heuristic).
// R11 combines the individually-proven pieces:
//  - 6-WG/64j (R6): 48 MFMA/wave, 48 CUs.
//  - GATE-LOCAL waves (R7): wave owns j-tile w x all 4 gates -> acc[gate][r] holds
//    i,f,g,o of the same (batch,j) -> cell is pure register math, NO preact LDS,
//    4 elems/thread (trans-wall 624->416cy).
//  - own chunk in DOUBLE-BUFFERED LDS + ONE lgkm barrier/step (fixes R7's L2
//    own-chunk regression; write buf[it&1], read buf[(it-1)&1], barrier separates).
//  - R10's vmcnt discipline: 20 exch loads up-front, counted polls 16/12/8/4/0,
//    retries via vmcnt(0) on an L2-only queue, 16 asm-ci loads issued AFTER the
//    last poll, drained by next step's WAIT(20) (ci16+stores8 = 24 drained of 44).
__launch_bounds__(256, 1)
__global__ void k_recur(const u16* __restrict__ whhpack, const u16* __restrict__ xg,
                        const float* __restrict__ biascat, const u16* __restrict__ h0buf,
                        const float* __restrict__ c0, u16* __restrict__ hout,
                        int* __restrict__ flags, u32* __restrict__ xch) {
    const int blk = blockIdx.x;      // 0..47
    const int qc = blk >> 3;         // j-chunk 0..5
    const int cl = blk & 7;          // cluster id
    const int d = cl >> 2;           // direction
    const int g = cl & 3;            // batch group (16 batches)
    const int tid = threadIdx.x, lane = tid & 63, w = tid >> 6;  // w = 16-j tile
    const int q4 = lane >> 4, l15 = lane & 15;

    __shared__ u16 hlds[2][16 * 72];   // own 64-j chunk, double-buffered, pad 72
    __shared__ int s_fast;

    // stationary Whh B-fragments: bfr[gate][j], j=2i+(0|1) = (lo|hi) 32-k slice of
    // chunk (qc+i)%6 (i=0 own). 48 frags; overflow spills to AGPR (unified file,
    // MFMA reads AGPR directly -> free).
    bf16x8 bfr[4][12];
    #pragma unroll
    for (int gg = 0; gg < 4; gg++)
        #pragma unroll
        for (int j = 0; j < 12; j++) {
            int ksg = 2 * ((qc + (j >> 1)) % NQC) + (j & 1);
            bfr[gg][j] = *(const bf16x8*)(whhpack +
                ((size_t)((((d * NQC + qc) * 4 + w) * 4 + gg) * 12 + ksg) * 64 + lane) * 8);
        }

    // c-state: thread owns (batch=q4*4+r, j=w*16+l15), r=0..3
    float cre[4];
    #pragma unroll
    for (int r = 0; r < 4; r++)
        cre[r] = c0[(size_t)(d * NB + g * 16 + q4 * 4 + r) * NH + qc * 64 + w * 16 + l15];
    float biasreg[4];
    #pragma unroll
    for (int gg = 0; gg < 4; gg++)
        biasreg[gg] = biascat[d * NG + gg * NH + qc * 64 + w * 16 + l15];

    // ---- co-location probe + consensus (once per launch) ----
    if (tid == 0) {
        int* pzb = flags + cl * 128;          // probe words (6 used, 64B spread)
        int* pmb = flags + 2048 + cl * 128;   // consensus masks
        st_sc0(pzb + qc * 16, MAGIC);
        u32 seen = 1u << qc;
        for (int spin = 0; spin < 768 && seen != 0x3Fu; ++spin) {
            #pragma unroll
            for (int r = 0; r < NQC; ++r)
                if (!((seen >> r) & 1u) && ld_sc0(pzb + r * 16) == MAGIC) seen |= 1u << r;
            __builtin_amdgcn_s_sleep(2);
        }
        __hip_atomic_store(pmb + qc * 16, (int)(0x100u | seen),
                           __ATOMIC_RELAXED, __HIP_MEMORY_SCOPE_AGENT);
        u32 m = 0x3Fu;
        int spin2 = 0;
        #pragma unroll
        for (int r = 0; r < NQC; ++r) {
            u32 v;
            do {
                v = (u32)__hip_atomic_load(pmb + r * 16, __ATOMIC_RELAXED,
                                           __HIP_MEMORY_SCOPE_AGENT);
            } while (!(v & 0x100u) && ++spin2 < MAX_RETRY);
            m &= v;
        }
        s_fast = ((m & 0x3Fu) == 0x3Fu && spin2 < MAX_RETRY) ? 1 : 0;
    }
    __syncthreads();
    const bool fast = (s_fast != 0);

    const u16* xgd = xg + (size_t)d * NB * S2 * NG;

    // ci preload: 16 asm ushort loads (4 gates x 4 batch-rows), counted in the
    // vmcnt ledger. Always issues (clamped row) so the ledger is constant.
    u32 cr[4][4];
    auto issue_preload = [&](int it2) -> bool {
        int s2 = d ? (NS - 1 - it2) : it2;
        bool ok = (s2 >= 0) && (s2 < S2);
        int s2c = min(max(s2, 0), S2 - 1);
        const u16* rp = xgd + ((size_t)(g * 16 + q4 * 4) * S2 + s2c) * NG
                        + qc * 64 + w * 16 + l15;
        #pragma unroll
        for (int r = 0; r < 4; r++) {
            asm volatile(
                "global_load_ushort %0, %4, off\n\t"
                "global_load_ushort %1, %4, off offset:768\n\t"
                "global_load_ushort %2, %4, off offset:1536\n\t"
                "global_load_ushort %3, %4, off offset:2304"
                : "=&v"(cr[0][r]), "=&v"(cr[1][r]), "=&v"(cr[2][r]), "=&v"(cr[3][r])
                : "v"(rp) : "memory");
            rp += (size_t)S2 * NG;
        }
        return ok;
    };
    bool vld = issue_preload(0);

    #pragma unroll 1
    for (int it = 0; it < NS; ++it) {
        int s = d ? (NS - 1 - it) : it;
        f32x4 acc[4];

        if (it == 0) {
            WAIT_VM(0);   // ci(0) ready
            #pragma unroll
            for (int gg = 0; gg < 4; gg++)
                #pragma unroll
                for (int r = 0; r < 4; r++)
                    acc[gg][r] = vld ? __uint_as_float(cr[gg][r] << 16) : biasreg[gg];
            vld = issue_preload(1);
            const u16* hp = h0buf + (size_t)(d * NB + g * 16) * NH;
            #pragma unroll
            for (int j = 0; j < 12; j++) {
                int ksg = 2 * ((qc + (j >> 1)) % NQC) + (j & 1);
                bf16x8 af = *(const bf16x8*)(hp + (size_t)l15 * NH + ksg * 32 + q4 * 8);
                #pragma unroll
                for (int gg = 0; gg < 4; gg++)
                    acc[gg] = __builtin_amdgcn_mfma_f32_16x16x32_bf16(af, bfr[gg][j], acc[gg], 0, 0, 0);
            }
        } else {
            const u32 T = (u32)it;
            const u32 want = T * 16u;
            u32* xb = xch + (size_t)((T & 3u) * 8 + cl) * (NQC * 1024)
                          + (u32)(l15 * 64 + q4 * 8);
            u32* p1 = xb + ((qc + 1) % NQC) * 1024;
            u32* p2 = xb + ((qc + 2) % NQC) * 1024;
            u32* p3 = xb + ((qc + 3) % NQC) * 1024;
            u32* p4 = xb + ((qc + 4) % NQC) * 1024;
            u32* p5 = xb + ((qc + 5) % NQC) * 1024;
            u32x4 r10, r11, r12, r13, r20, r21, r22, r23, r30, r31, r32, r33;
            u32x4 r40, r41, r42, r43, r50, r51, r52, r53;
            // entering: ci(16)+stores(8)=24 outstanding; issue 20 exch -> 44
            ld4_nw(fast, p1, r10, r11, r12, r13);
            ld4_nw(fast, p2, r20, r21, r22, r23);
            ld4_nw(fast, p3, r30, r31, r32, r33);
            ld4_nw(fast, p4, r40, r41, r42, r43);
            ld4_nw(fast, p5, r50, r51, r52, r53);
            WAIT_VM(20);   // drains ci+stores; leaves exactly the 20 exch loads
            #pragma unroll
            for (int gg = 0; gg < 4; gg++)
                #pragma unroll
                for (int r = 0; r < 4; r++)
                    acc[gg][r] = vld ? __uint_as_float(cr[gg][r] << 16) : biasreg[gg];
            // own chunk from double-buffered LDS (written by cell of step it-1)
            {
                const u16* hb = &hlds[(it - 1) & 1][0];
                bf16x8 afo0 = *(const bf16x8*)&hb[l15 * 72 + q4 * 8];
                bf16x8 afo1 = *(const bf16x8*)&hb[l15 * 72 + 32 + q4 * 8];
                #pragma unroll
                for (int gg = 0; gg < 4; gg++)
                    acc[gg] = __builtin_amdgcn_mfma_f32_16x16x32_bf16(afo0, bfr[gg][0], acc[gg], 0, 0, 0);
                #pragma unroll
                for (int gg = 0; gg < 4; gg++)
                    acc[gg] = __builtin_amdgcn_mfma_f32_16x16x32_bf16(afo1, bfr[gg][1], acc[gg], 0, 0, 0);
            }
            int tries;
            // chunk 1 (oldest of the 20)
            WAIT_VM(16);
            tries = 0;
            while (!__all(sum4(r10, r11, r12, r13) == want) && ++tries < MAX_RETRY)
                ld4_wt(fast, p1, r10, r11, r12, r13);   // vmcnt(0): L2-only queue
            {
                bf16x8 lo = packf(r10, r11), hi = packf(r12, r13);
                #pragma unroll
                for (int gg = 0; gg < 4; gg++)
                    acc[gg] = __builtin_amdgcn_mfma_f32_16x16x32_bf16(lo, bfr[gg][2], acc[gg], 0, 0, 0);
                #pragma unroll
                for (int gg = 0; gg < 4; gg++)
                    acc[gg] = __builtin_amdgcn_mfma_f32_16x16x32_bf16(hi, bfr[gg][3], acc[gg], 0, 0, 0);
            }
            // chunk 2
            WAIT_VM(12);
            tries = 0;
            while (!__all(sum4(r20, r21, r22, r23) == want) && ++tries < MAX_RETRY)
                ld4_wt(fast, p2, r20, r21, r22, r23);
            {
                bf16x8 lo = packf(r20, r21), hi = packf(r22, r23);
                #pragma unroll
                for (int gg = 0; gg < 4; gg++)
                    acc[gg] = __builtin_amdgcn_mfma_f32_16x16x32_bf16(lo, bfr[gg][4], acc[gg], 0, 0, 0);
                #pragma unroll
                for (int gg = 0; gg < 4; gg++)
                    acc[gg] = __builtin_amdgcn_mfma_f32_16x16x32_bf16(hi, bfr[gg][5], acc[gg], 0, 0, 0);
            }
            // chunk 3
            WAIT_VM(8);
            tries = 0;
            while (!__all(sum4(r30, r31, r32, r33) == want) && ++tries < MAX_RETRY)
                ld4_wt(fast, p3, r30, r31, r32, r33);
            {
                bf16x8 lo = packf(r30, r31), hi = packf(r32, r33);
                #pragma unroll
                for (int gg = 0; gg < 4; gg++)
                    acc[gg] = __builtin_amdgcn_mfma_f32_16x16x32_bf16(lo, bfr[gg][6], acc[gg], 0, 0, 0);
                #pragma unroll
                for (int gg = 0; gg < 4; gg++)
                    acc[gg] = __builtin_amdgcn_mfma_f32_16x16x32_bf16(hi, bfr[gg][7], acc[gg], 0, 0, 0);
            }
            // chunk 4
            WAIT_VM(4);
            tries = 0;
            while (!__all(sum4(r40, r41, r42, r43) == want) && ++tries < MAX_RETRY)
                ld4_wt(fast, p4, r40, r41, r42, r43);
            {
                bf16x8 lo = packf(r40, r41), hi = packf(r42, r43);
                #pragma unroll
                for (int gg = 0; gg < 4; gg++)
                    acc[gg] = __builtin_amdgcn_mfma_f32_16x16x32_bf16(lo, bfr[gg][8], acc[gg], 0, 0, 0);
                #pragma unroll
                for (int gg = 0; gg < 4; gg++)
                    acc[gg] = __builtin_amdgcn_mfma_f32_16x16x32_bf16(hi, bfr[gg][9], acc[gg], 0, 0, 0);
            }
            // chunk 5
            WAIT_VM(0);
            tries = 0;
            while (!__all(sum4(r50, r51, r52, r53) == want) && ++tries < MAX_RETRY)
                ld4_wt(fast, p5, r50, r51, r52, r53);
            vld = issue_preload(it + 1);   // ci AFTER polls: hides under cell+barrier
            {
                bf16x8 lo = packf(r50, r51), hi = packf(r52, r53);
                #pragma unroll
                for (int gg = 0; gg < 4; gg++)
                    acc[gg] = __builtin_amdgcn_mfma_f32_16x16x32_bf16(lo, bfr[gg][10], acc[gg], 0, 0, 0);
                #pragma unroll
                for (int gg = 0; gg < 4; gg++)
                    acc[gg] = __builtin_amdgcn_mfma_f32_16x16x32_bf16(hi, bfr[gg][11], acc[gg], 0, 0, 0);
            }
        }

        // cell update: fully register-local (acc[gate][r] = i,f,g,o of same (b,j))
        {
            u32 t2 = (u32)it + 1u;
            u16 hv[4];
            #pragma unroll
            for (int r = 0; r < 4; r++) {
                float gi = acc[0][r], gf = acc[1][r];
                float gz = acc[2][r], go = acc[3][r];
                float c = cre[r];
                float cn = sigm(gf) * c + sigm(gi) * tanh_(gz);
                float hn = sigm(go) * tanh_(cn);
                cre[r] = cn;
                hv[r] = f2b(hn);
            }
            u32 tg0 = ((u32)hv[0] << 16) | t2, tg1 = ((u32)hv[1] << 16) | t2;
            u32 tg2 = ((u32)hv[2] << 16) | t2, tg3 = ((u32)hv[3] << 16) | t2;
            // tagged publish FIRST: 4 dwords at batch stride 64 words (256 B)
            u32* xp = xch + (size_t)((t2 & 3u) * 8 + cl) * (NQC * 1024)
                          + (u32)(qc * 1024 + (q4 * 4) * 64 + w * 16 + l15);
            if (fast)
                asm volatile(
                    "global_store_dword %0, %1, off sc0\n\t"
                    "global_store_dword %0, %2, off offset:256 sc0\n\t"
                    "global_store_dword %0, %3, off offset:512 sc0\n\t"
                    "global_store_dword %0, %4, off offset:768 sc0"
                    :: "v"(xp), "v"(tg0), "v"(tg1), "v"(tg2), "v"(tg3) : "memory");
            else {
                __hip_atomic_store(xp,       tg0, __ATOMIC_RELAXED, __HIP_MEMORY_SCOPE_AGENT);
                __hip_atomic_store(xp + 64,  tg1, __ATOMIC_RELAXED, __HIP_MEMORY_SCOPE_AGENT);
                __hip_atomic_store(xp + 128, tg2, __ATOMIC_RELAXED, __HIP_MEMORY_SCOPE_AGENT);
                __hip_atomic_store(xp + 192, tg3, __ATOMIC_RELAXED, __HIP_MEMORY_SCOPE_AGENT);
            }
            // output history (plain cached, batch-strided)
            size_t hob = ((size_t)(d * NB + g * 16 + q4 * 4) * NS + s) * NH
                         + qc * 64 + w * 16 + l15;
            hout[hob] = hv[0];
            hout[hob + (size_t)NS * NH] = hv[1];
            hout[hob + (size_t)2 * NS * NH] = hv[2];
            hout[hob + (size_t)3 * NS * NH] = hv[3];
            // own chunk -> double-buffered LDS for next step
            u16* hb = &hlds[it & 1][0];
            hb[(q4 * 4 + 0) * 72 + w * 16 + l15] = hv[0];
            hb[(q4 * 4 + 1) * 72 + w * 16 + l15] = hv[1];
            hb[(q4 * 4 + 2) * 72 + w * 16 + l15] = hv[2];
            hb[(q4 * 4 + 3) * 72 + w * 16 + l15] = hv[3];
        }
        ldsbar();   // the ONLY barrier per step (lgkm-only)
    }
}

// ---------------- final linear: out[b,t,22] = [hf|hb] @ WlinT + blin ----------------
__global__ void k_final(const u16* __restrict__ hout, const float* __restrict__ wlin,
                        const float* __restrict__ blin, float* __restrict__ out) {
    int r = blockIdx.x * 256 + threadIdx.x;   // 0..32767
    int b = r >> 9, t = r & 511;
    const u16* hf = hout + ((size_t)b * NS + t) * NH;
    const u16* hb = hout + ((size_t)(NB + b) * NS + t) * NH;
    float acc[NT_OUT];
    #pragma unroll
    for (int tt = 0; tt < NT_OUT; tt++) acc[tt] = blin[tt];
    #pragma unroll 1
    for (int half = 0; half < 2; half++) {
        const u16* hp = half ? hb : hf;
        #pragma unroll 1
        for (int k8 = 0; k8 < NH / 8; k8++) {
            uint4 pk = *(const uint4*)(hp + k8 * 8);
            float x[8];
            x[0] = __uint_as_float(pk.x << 16); x[1] = __uint_as_float(pk.x & 0xffff0000u);
            x[2] = __uint_as_float(pk.y << 16); x[3] = __uint_as_float(pk.y & 0xffff0000u);
            x[4] = __uint_as_float(pk.z << 16); x[5] = __uint_as_float(pk.z & 0xffff0000u);
            x[6] = __uint_as_float(pk.w << 16); x[7] = __uint_as_float(pk.w & 0xffff0000u);
            int kk = half * NH + k8 * 8;
            #pragma unroll
            for (int e = 0; e < 8; e++)
                #pragma unroll
                for (int tt = 0; tt < NT_OUT; tt++)
                    acc[tt] += x[e] * wlin[tt * (2 * NH) + kk + e];   // uniform -> s_load
        }
    }
    float* op = out + (size_t)r * NT_OUT;
    #pragma unroll
    for (int tt = 0; tt < NT_OUT; tt++) op[tt] = acc[tt];
}

extern "C" void kernel_launch(void* const* d_in, const int* in_sizes, int n_in,
                              void* d_out, int out_size, void* d_ws, size_t ws_size,
                              hipStream_t stream) {
    const float* hidden = (const float*)d_in[0];
    const float* h0     = (const float*)d_in[1];
    const float* c0     = (const float*)d_in[2];
    const float* Wihf   = (const float*)d_in[3];
    const float* Whhf   = (const float*)d_in[4];
    const float* bihf   = (const float*)d_in[5];
    const float* bhhf   = (const float*)d_in[6];
    const float* Wihb   = (const float*)d_in[7];
    const float* Whhb   = (const float*)d_in[8];
    const float* bihb   = (const float*)d_in[9];
    const float* bhhb   = (const float*)d_in[10];
    const float* Wlin   = (const float*)d_in[11];
    const float* blin   = (const float*)d_in[12];
    const int* start_ids = (const int*)d_in[13];
    const int* masks     = (const int*)d_in[14];
    float* out = (float*)d_out;

    char* ws = (char*)d_ws;
    size_t off = 0;
    auto alloc = [&](size_t bytes) { void* p = ws + off; off += (bytes + 255) & ~(size_t)255; return p; };
    u16* embeds   = (u16*)alloc((size_t)MGEMM * ND * 2);           // 26.7 MB
    u16* wihcat   = (u16*)alloc((size_t)2 * NG * ND * 2);          // 4.7 MB
    float* biascat = (float*)alloc((size_t)2 * NG * 4);            // 12 KB
    u16* whhpack  = (u16*)alloc((size_t)2 * NG * NH * 2);          // 2.36 MB
    u16* h0buf    = (u16*)alloc((size_t)2 * NB * NH * 2);          // 98 KB
    u16* xg       = (u16*)alloc((size_t)2 * NB * S2 * NG * 2);     // 107 MB
    u16* hout     = (u16*)alloc((size_t)2 * NB * NS * NH * 2);     // 50.3 MB
    int* flags    = (int*)alloc((size_t)8 * NS * 4);               // 16 KB (probe+consensus)
    u32* xch      = (u32*)alloc((size_t)4 * 8 * NQC * 1024 * 4);   // 786 KB tagged h exchange

    (void)hipMemsetAsync(flags, 0, (size_t)8 * NS * 4, stream);
    (void)hipMemsetAsync(xch, 0, (size_t)4 * 8 * NQC * 1024 * 4, stream);
    k_prep<<<256, 256, 0, stream>>>(hidden, start_ids, masks, embeds);
    k_weights<<<512, 256, 0, stream>>>(Wihf, Wihb, bihf, bhhf, bihb, bhhb, h0,
                                       wihcat, biascat, h0buf);
    k_packwhh<<<576, 256, 0, stream>>>(Whhf, Whhb, whhpack);
    dim3 ggrid(2 * NG / 128, MGEMM / 128);
    k_gemm<<<ggrid, 256, 0, stream>>>(embeds, wihcat, biascat, xg);
    k_recur<<<48, 256, 0, stream>>>(whhpack, xg, biascat, h0buf, c0, hout, flags, xch);
    k_final<<<128, 256, 0, stream>>>(hout, Wlin, blin, out);
}